// Round 4
// baseline (910.375 us; speedup 1.0000x reference)
//
#include <hip/hip_runtime.h>
#include <cstddef>
#include <cstdint>

#define VOCAB  32000
#define EMB    256
#define NB     8
#define KDIM   2048        /* H*NB */
#define NROWS  1024        /* B*L  */
#define NCOL   4096        /* 2*KDIM */
#define LLEN   256

typedef __attribute__((ext_vector_type(8))) short short8;
typedef __attribute__((ext_vector_type(4))) float f32x4;
typedef __attribute__((ext_vector_type(16))) float f32x16;

__device__ __forceinline__ float cl3_sign(int a, int b) {
  int x = a >> 1, p = 0;
  while (x) { p ^= __popc(x & b) & 1; x >>= 1; }
  return p ? -1.f : 1.f;   // metric all +1 for Cl(3,0)
}

__device__ __forceinline__ float clipf(float v) { return fminf(fmaxf(v, 0.f), 1.f); }

__device__ __forceinline__ unsigned short f2bf(float f) {
  unsigned u = __float_as_uint(f);
  u += 0x7FFF + ((u >> 16) & 1);           // round-to-nearest-even
  return (unsigned short)(u >> 16);
}
__device__ __forceinline__ float bf2f(unsigned short h) {
  return __uint_as_float(((unsigned)h) << 16);
}

// chunk-major tiled offset: tile = 128 rows x 32 k stored as [4 kchunk][128 row][8 k]
// tiles linear: tr*64 + tk  (K=2048 -> 64 k-tiles)
__device__ __forceinline__ size_t tso128(int tr, int tk, int r, int kk) {
  return ((size_t)(tr * 64 + tk) << 12) + ((size_t)((kk >> 3) & 3) << 10) + (r << 3) + (kk & 7);
}

__device__ __forceinline__ void gload16(const void* g, void* l) {
  __builtin_amdgcn_global_load_lds((const __attribute__((address_space(1))) uint32_t*)g,
                                   (__attribute__((address_space(3))) uint32_t*)l, 16, 0, 0);
}

// ---- MRT split build: B^T [4096][2048] -> chunk-major tiled hi/lo bf16 ----
__global__ void k_build_mrt_split(const float* __restrict__ Wrec,
                                  unsigned short* __restrict__ Mhi,
                                  unsigned short* __restrict__ Mlo) {
  int idx = blockIdx.x * blockDim.x + threadIdx.x;
  int k = idx & (KDIM - 1);
  int n = idx >> 11;
  int h = k >> 3, i = k & 7;
  float v;
  if (n < KDIM) {
    int g = n >> 3, kb = n & 7;
    int j = i ^ kb;
    v = Wrec[(size_t)g * KDIM + h * NB + j] * cl3_sign(i, j);
  } else {
    int c = n - KDIM;
    int p = c >> 3, q = c & 7;
    int j = q ^ i;
    v = cl3_sign(i, i) * cl3_sign(q, j) * Wrec[(size_t)h * KDIM + p * NB + j];
  }
  unsigned short hi = f2bf(v);
  unsigned short lo = f2bf(v - bf2f(hi));
  size_t off = tso128(n >> 7, k >> 5, n & 127, k & 31);
  Mhi[off] = hi; Mlo[off] = lo;
}

// ---- Wout converter: one block = one 128x32 tile; LDS-staged for coalesced writes ----
__global__ __launch_bounds__(256) void k_conv_wout(const float* __restrict__ W,
                                                   unsigned short* __restrict__ Whi,
                                                   unsigned short* __restrict__ Wlo) {
  __shared__ unsigned short shi[4096], slo[4096];
  const int tile = blockIdx.x;            // tr*64 + tk, 250*64 tiles
  const int tr = tile >> 6, tk = tile & 63;
  const int t = threadIdx.x;
  const int row = t >> 1, half = t & 1;   // 2 threads per row, 16 floats each
  const float* src = W + (size_t)(tr * 128 + row) * KDIM + tk * 32 + half * 16;
  float e[16];
#pragma unroll
  for (int q = 0; q < 4; ++q)
    *(float4*)&e[q * 4] = *(const float4*)(src + q * 4);
  short8 h8[2], l8[2];
#pragma unroll
  for (int j = 0; j < 16; ++j) {
    unsigned short hi = f2bf(e[j]);
    h8[j >> 3][j & 7] = (short)hi;
    l8[j >> 3][j & 7] = (short)f2bf(e[j] - bf2f(hi));
  }
  const int base = (half * 2) << 10;
#pragma unroll
  for (int q = 0; q < 2; ++q) {
    *(short8*)&shi[base + (q << 10) + row * 8] = h8[q];
    *(short8*)&slo[base + (q << 10) + row * 8] = l8[q];
  }
  __syncthreads();
  size_t ob = ((size_t)tile << 12) + t * 16;
#pragma unroll
  for (int q = 0; q < 2; ++q) {
    *(short8*)&Whi[ob + q * 8] = *(short8*)&shi[t * 16 + q * 8];
    *(short8*)&Wlo[ob + q * 8] = *(short8*)&slo[t * 16 + q * 8];
  }
}

// input_mv[r][h*8+i] = sum_d emb[x[r]][d] * Win[h][d][i]; one block = 4 rows
__global__ __launch_bounds__(256) void k_input_mv(const int* __restrict__ x,
                                                  const float* __restrict__ emb,
                                                  const float* __restrict__ Win,
                                                  float* __restrict__ out) {
  __shared__ float se[4][EMB];
  int r0 = blockIdx.x * 4;
  int t = threadIdx.x;
  for (int rr = 0; rr < 4; ++rr) {
    int tok = x[r0 + rr];
    se[rr][t] = emb[(size_t)tok * EMB + t];
  }
  __syncthreads();
  float acc[4][8];
#pragma unroll
  for (int rr = 0; rr < 4; ++rr)
#pragma unroll
    for (int i = 0; i < 8; ++i) acc[rr][i] = 0.f;
  const float* wrow = Win + (size_t)t * KDIM;
  for (int d = 0; d < EMB; ++d) {
    float4 w0 = *(const float4*)(wrow + d * 8);
    float4 w1 = *(const float4*)(wrow + d * 8 + 4);
#pragma unroll
    for (int rr = 0; rr < 4; ++rr) {
      float e = se[rr][d];
      acc[rr][0] += e * w0.x; acc[rr][1] += e * w0.y;
      acc[rr][2] += e * w0.z; acc[rr][3] += e * w0.w;
      acc[rr][4] += e * w1.x; acc[rr][5] += e * w1.y;
      acc[rr][6] += e * w1.z; acc[rr][7] += e * w1.w;
    }
  }
  for (int rr = 0; rr < 4; ++rr) {
    float4* o = (float4*)(out + (size_t)(r0 + rr) * KDIM + t * 8);
    o[0] = make_float4(acc[rr][0], acc[rr][1], acc[rr][2], acc[rr][3]);
    o[1] = make_float4(acc[rr][4], acc[rr][5], acc[rr][6], acc[rr][7]);
  }
}

// ---- pure bf16 split GEMM, 32x32x16 MFMA, chunk-major conflict-free LDS ----
// C = (Ahi+Alo)(Bhi+Blo)^T (3-pass, al*bl dropped). Tiles 128x128, 4 waves.
__global__ __launch_bounds__(256, 2) void k_gemm_pre(const unsigned short* __restrict__ Ahi,
                                                     const unsigned short* __restrict__ Alo,
                                                     const unsigned short* __restrict__ Bhi,
                                                     const unsigned short* __restrict__ Blo,
                                                     float* __restrict__ C, int ldc) {
  __shared__ __align__(16) unsigned short lds[2][4][4096];
  const int nwg = gridDim.x;
  const int b = blockIdx.x;
  const int lin = (b & 7) * (nwg >> 3) + (b >> 3);   // XCD-chunked swizzle (nwg%8==0)
  const int tn = lin >> 3, tm = lin & 7;             // 8 consecutive lin share B-panel
  const int t = threadIdx.x;
  const int l = t & 63, w = t >> 6;
  const int wr = w >> 1, wc = w & 1;

  const unsigned short* aH = Ahi + ((size_t)tm * 64 << 12);
  const unsigned short* aL = Alo + ((size_t)tm * 64 << 12);
  const unsigned short* bH = Bhi + ((size_t)tn * 64 << 12);
  const unsigned short* bL = Blo + ((size_t)tn * 64 << 12);

  const int ldso0 = w * 1024;          // wave-uniform LDS dest (elements)
  const int ldso1 = ldso0 + 512;
  const int srco0 = ldso0 + (l << 3);
  const int srco1 = ldso1 + (l << 3);

  const int rA0 = wr * 64 + (l & 31);
  const int rB0 = wc * 64 + (l & 31);
  const int ch0 = l >> 5;

  f32x16 acc[2][2];
#pragma unroll
  for (int i = 0; i < 2; ++i)
#pragma unroll
    for (int j = 0; j < 2; ++j) acc[i][j] = (f32x16)0.f;

  auto STAGE = [&](int bf, int kt) {
    size_t kb = (size_t)kt << 12;
    gload16(aH + kb + srco0, &lds[bf][0][ldso0]);
    gload16(aH + kb + srco1, &lds[bf][0][ldso1]);
    gload16(aL + kb + srco0, &lds[bf][1][ldso0]);
    gload16(aL + kb + srco1, &lds[bf][1][ldso1]);
    gload16(bH + kb + srco0, &lds[bf][2][ldso0]);
    gload16(bH + kb + srco1, &lds[bf][2][ldso1]);
    gload16(bL + kb + srco0, &lds[bf][3][ldso0]);
    gload16(bL + kb + srco1, &lds[bf][3][ldso1]);
  };

  STAGE(0, 0);
  __syncthreads();
  int cur = 0;
  for (int kt = 0; kt < 64; ++kt) {
    if (kt < 63) STAGE(cur ^ 1, kt + 1);
#pragma unroll
    for (int s = 0; s < 2; ++s) {
      const int cb = (s * 2 + ch0) << 10;
      short8 ah[2], al[2], bh[2], bl[2];
#pragma unroll
      for (int mi = 0; mi < 2; ++mi) {
        ah[mi] = *(const short8*)&lds[cur][0][cb + ((rA0 + mi * 32) << 3)];
        al[mi] = *(const short8*)&lds[cur][1][cb + ((rA0 + mi * 32) << 3)];
      }
#pragma unroll
      for (int nj = 0; nj < 2; ++nj) {
        bh[nj] = *(const short8*)&lds[cur][2][cb + ((rB0 + nj * 32) << 3)];
        bl[nj] = *(const short8*)&lds[cur][3][cb + ((rB0 + nj * 32) << 3)];
      }
#pragma unroll
      for (int mi = 0; mi < 2; ++mi)
#pragma unroll
        for (int nj = 0; nj < 2; ++nj) {
          acc[mi][nj] = __builtin_amdgcn_mfma_f32_32x32x16_bf16(ah[mi], bh[nj], acc[mi][nj], 0, 0, 0);
          acc[mi][nj] = __builtin_amdgcn_mfma_f32_32x32x16_bf16(ah[mi], bl[nj], acc[mi][nj], 0, 0, 0);
          acc[mi][nj] = __builtin_amdgcn_mfma_f32_32x32x16_bf16(al[mi], bh[nj], acc[mi][nj], 0, 0, 0);
        }
    }
    __syncthreads();
    cur ^= 1;
  }

  // C/D layout (m74/m101): col = lane&31, row = (reg&3) + 8*(reg>>2) + 4*(lane>>5)
  const int rg0 = tm * 128 + wr * 64 + ((l >> 5) << 2);
  const int cg0 = tn * 128 + wc * 64 + (l & 31);
#pragma unroll
  for (int mi = 0; mi < 2; ++mi)
#pragma unroll
    for (int nj = 0; nj < 2; ++nj) {
      f32x16 v = acc[mi][nj];
#pragma unroll
      for (int g = 0; g < 16; ++g) {
        int rr = (g & 3) + ((g >> 2) << 3);
        C[(size_t)(rg0 + mi * 32 + rr) * ldc + cg0 + nj * 32] = v[g];
      }
    }
}

// h <- h - 0.1*(h - drho(h)*(inmv*sq + rec_prev*sq + fwd_next)); emits split A for next GEMM
template <int LAST>
__global__ __launch_bounds__(256) void k_update(float* __restrict__ Hb, const float* __restrict__ Imv,
                                                const float* __restrict__ RF,
                                                unsigned short* __restrict__ Hhi,
                                                unsigned short* __restrict__ Hlo) {
  int idx = blockIdx.x * 256 + threadIdx.x;   // 262144 threads, 8 elems each
  int r = idx >> 8;
  int c = (idx & 255) << 3;
  int m = r & (LLEN - 1);
  const size_t base = (size_t)r * KDIM + c;
  float h[8], f[8];
  *(float4*)&h[0] = *(const float4*)(Hb + base);
  *(float4*)&h[4] = *(const float4*)(Hb + base + 4);
  float4 i0 = *(const float4*)(Imv + base);
  float4 i1 = *(const float4*)(Imv + base + 4);
  f[0] = i0.x; f[1] = i0.y; f[2] = i0.z; f[3] = i0.w;
  f[4] = i1.x; f[5] = i1.y; f[6] = i1.z; f[7] = i1.w;
#pragma unroll
  for (int j = 0; j < 8; ++j) f[j] *= ((0xE8 >> j) & 1) ? -1.f : 1.f;
  if (m >= 1) {
    const float* rp = RF + (size_t)(r - 1) * NCOL + c;
    float4 p0 = *(const float4*)rp;
    float4 p1 = *(const float4*)(rp + 4);
    float p[8] = {p0.x, p0.y, p0.z, p0.w, p1.x, p1.y, p1.z, p1.w};
#pragma unroll
    for (int j = 0; j < 8; ++j) f[j] += p[j] * (((0xE8 >> j) & 1) ? -1.f : 1.f);
  }
  if (m < LLEN - 1) {
    const float* rn = RF + (size_t)(r + 1) * NCOL + KDIM + c;
    float4 n0 = *(const float4*)rn;
    float4 n1 = *(const float4*)(rn + 4);
    f[0] += n0.x; f[1] += n0.y; f[2] += n0.z; f[3] += n0.w;
    f[4] += n1.x; f[5] += n1.y; f[6] += n1.z; f[7] += n1.w;
  }
  float hn[8];
  short8 h8, l8;
#pragma unroll
  for (int j = 0; j < 8; ++j) {
    float hv = h[j];
    float dr = (hv > 0.f && hv < 1.f) ? 1.f : ((hv == 0.f || hv == 1.f) ? 0.5f : 0.f);
    hn[j] = hv - 0.1f * (hv - dr * f[j]);
    float av = LAST ? hn[j] * (((0xE8 >> j) & 1) ? -1.f : 1.f) : clipf(hn[j]);
    unsigned short hi = f2bf(av);
    h8[j] = (short)hi;
    l8[j] = (short)f2bf(av - bf2f(hi));
  }
  *(float4*)(Hb + base) = make_float4(hn[0], hn[1], hn[2], hn[3]);
  *(float4*)(Hb + base + 4) = make_float4(hn[4], hn[5], hn[6], hn[7]);
  size_t off = tso128(r >> 7, c >> 5, r & 127, c & 31);
  *(short8*)&Hhi[off] = h8;
  *(short8*)&Hlo[off] = l8;
}

// ---- round-2 fallback logits GEMM (in-kernel conversion), used if ws too small ----
template <int AMODE>
__global__ __launch_bounds__(256) void k_gemm_split(const float* __restrict__ A,
                                                    const float* __restrict__ B,
                                                    float* __restrict__ C, int ldc) {
  __shared__ unsigned short Ah[128 * 32], Al[128 * 32];
  __shared__ unsigned short Bh[128 * 32], Bl[128 * 32];
  const int t = threadIdx.x;
  const int row0 = blockIdx.y * 128, col0 = blockIdx.x * 128;
  const int l = t & 63, w = t >> 6;
  const int wr = w >> 1, wc = w & 1;
  const int sr = t >> 3;
  const int cc = (t & 7) << 2;
  const int chunkb = cc >> 3;
  const int halfo = (cc >> 2) & 1;
  f32x4 acc[4][4];
#pragma unroll
  for (int i = 0; i < 4; ++i)
#pragma unroll
    for (int j = 0; j < 4; ++j) acc[i][j] = (f32x4)0.f;
  const float sA0 = 1.f;
  const float sA1 = (cc & 4) ? -1.f : 1.f;
  const float sA2 = sA1;
  const float sA3 = -1.f;
  for (int k0 = 0; k0 < KDIM; k0 += 32) {
    float4 va[4], vb[4];
#pragma unroll
    for (int i = 0; i < 4; ++i) {
      va[i] = *(const float4*)(A + (size_t)(row0 + sr + i * 32) * KDIM + k0 + cc);
      vb[i] = *(const float4*)(B + (size_t)(col0 + sr + i * 32) * KDIM + k0 + cc);
    }
    __syncthreads();
#pragma unroll
    for (int i = 0; i < 4; ++i) {
      int row = sr + i * 32;
      int idx = row * 32 + ((chunkb ^ (row & 3)) << 3) + (halfo << 2);
      float4 a = va[i];
      if (AMODE == 0) {
        a.x = clipf(a.x); a.y = clipf(a.y); a.z = clipf(a.z); a.w = clipf(a.w);
      } else {
        a.x *= sA0; a.y *= sA1; a.z *= sA2; a.w *= sA3;
      }
      ushort4 h4, l4;
      h4.x = f2bf(a.x); l4.x = f2bf(a.x - bf2f(h4.x));
      h4.y = f2bf(a.y); l4.y = f2bf(a.y - bf2f(h4.y));
      h4.z = f2bf(a.z); l4.z = f2bf(a.z - bf2f(h4.z));
      h4.w = f2bf(a.w); l4.w = f2bf(a.w - bf2f(h4.w));
      *(ushort4*)&Ah[idx] = h4;
      *(ushort4*)&Al[idx] = l4;
      float4 bb = vb[i];
      h4.x = f2bf(bb.x); l4.x = f2bf(bb.x - bf2f(h4.x));
      h4.y = f2bf(bb.y); l4.y = f2bf(bb.y - bf2f(h4.y));
      h4.z = f2bf(bb.z); l4.z = f2bf(bb.z - bf2f(h4.z));
      h4.w = f2bf(bb.w); l4.w = f2bf(bb.w - bf2f(h4.w));
      *(ushort4*)&Bh[idx] = h4;
      *(ushort4*)&Bl[idx] = l4;
    }
    __syncthreads();
    short8 ah[4], al[4], bh[4], bl[4];
#pragma unroll
    for (int mi = 0; mi < 4; ++mi) {
      int ar = wr * 64 + mi * 16 + (l & 15);
      int kc = (l >> 4) ^ (ar & 3);
      ah[mi] = *(short8*)&Ah[ar * 32 + kc * 8];
      al[mi] = *(short8*)&Al[ar * 32 + kc * 8];
      int br = wc * 64 + mi * 16 + (l & 15);
      int kb = (l >> 4) ^ (br & 3);
      bh[mi] = *(short8*)&Bh[br * 32 + kb * 8];
      bl[mi] = *(short8*)&Bl[br * 32 + kb * 8];
    }
#pragma unroll
    for (int mi = 0; mi < 4; ++mi)
#pragma unroll
      for (int ni = 0; ni < 4; ++ni) {
        acc[mi][ni] = __builtin_amdgcn_mfma_f32_16x16x32_bf16(ah[mi], bh[ni], acc[mi][ni], 0, 0, 0);
        acc[mi][ni] = __builtin_amdgcn_mfma_f32_16x16x32_bf16(ah[mi], bl[ni], acc[mi][ni], 0, 0, 0);
        acc[mi][ni] = __builtin_amdgcn_mfma_f32_16x16x32_bf16(al[mi], bh[ni], acc[mi][ni], 0, 0, 0);
      }
  }
#pragma unroll
  for (int mi = 0; mi < 4; ++mi)
#pragma unroll
    for (int ni = 0; ni < 4; ++ni) {
      int rg = row0 + wr * 64 + mi * 16 + (l >> 4) * 4;
      int cg = col0 + wc * 64 + ni * 16 + (l & 15);
#pragma unroll
      for (int j = 0; j < 4; ++j)
        C[(size_t)(rg + j) * ldc + cg] = acc[mi][ni][j];
    }
}

extern "C" void kernel_launch(void* const* d_in, const int* in_sizes, int n_in,
                              void* d_out, int out_size, void* d_ws, size_t ws_size,
                              hipStream_t stream) {
  const int*   x    = (const int*)d_in[0];
  const float* emb  = (const float*)d_in[1];
  const float* Win  = (const float*)d_in[2];
  const float* Wrec = (const float*)d_in[3];
  const float* Wout = (const float*)d_in[4];
  float* logits = (float*)d_out;

  float* ws   = (float*)d_ws;
  float* Hbuf = ws;                          // 2M f   ( 8 MB)
  float* Imv  = ws + (1 << 21);              // 2M f   ( 8 MB)
  float* RF   = ws + (1 << 22);              // 4M f   (16 MB)
  unsigned short* Hhi = (unsigned short*)(ws + (1 << 23));   // 2M ush (4 MB)
  unsigned short* Hlo = Hhi + (1 << 21);                     // 2M ush
  unsigned short* Mhi = Hlo + (1 << 21);                     // 8M ush (16 MB)
  unsigned short* Mlo = Mhi + (1 << 23);                     // 8M ush
  unsigned short* Whi = Mlo + (1 << 23);                     // 65.536M ush (131 MB)
  unsigned short* Wlo = Whi + (size_t)VOCAB * KDIM;

  const size_t need = (size_t)75497472 + 2ull * VOCAB * KDIM * sizeof(unsigned short);
  const bool big = ws_size >= need;

  hipMemsetAsync(Hbuf, 0, (size_t)8 << 20, stream);
  hipMemsetAsync(Hhi, 0, (size_t)8 << 20, stream);   // Hhi + Hlo contiguous
  k_build_mrt_split<<<32768, 256, 0, stream>>>(Wrec, Mhi, Mlo);
  k_input_mv<<<256, 256, 0, stream>>>(x, emb, Win, Imv);
  if (big) k_conv_wout<<<16000, 256, 0, stream>>>(Wout, Whi, Wlo);

  for (int it = 0; it < 5; ++it) {
    k_gemm_pre<<<256, 256, 0, stream>>>(Hhi, Hlo, Mhi, Mlo, RF, NCOL);
    if (it < 4) k_update<0><<<1024, 256, 0, stream>>>(Hbuf, Imv, RF, Hhi, Hlo);
    else        k_update<1><<<1024, 256, 0, stream>>>(Hbuf, Imv, RF, Hhi, Hlo);
  }

  if (big) k_gemm_pre<<<2000, 256, 0, stream>>>(Hhi, Hlo, Whi, Wlo, logits, VOCAB);
  else     k_gemm_split<1><<<dim3(VOCAB / 128, NROWS / 128), 256, 0, stream>>>(Hbuf, Wout, logits, VOCAB);
}

// Round 5
// 802.536 us; speedup vs baseline: 1.1344x; 1.1344x over previous
//
#include <hip/hip_runtime.h>
#include <cstddef>
#include <cstdint>

#define VOCAB  32000
#define EMB    256
#define NB     8
#define KDIM   2048        /* H*NB */
#define NROWS  1024        /* B*L  */
#define NCOL   4096        /* 2*KDIM */
#define LLEN   256

typedef __attribute__((ext_vector_type(8))) short short8;
typedef __attribute__((ext_vector_type(4))) float f32x4;
typedef __attribute__((ext_vector_type(16))) float f32x16;
typedef __attribute__((ext_vector_type(4))) int i32x4;
typedef __attribute__((ext_vector_type(16))) int i32x16;

__device__ __forceinline__ float cl3_sign(int a, int b) {
  int x = a >> 1, p = 0;
  while (x) { p ^= __popc(x & b) & 1; x >>= 1; }
  return p ? -1.f : 1.f;   // metric all +1 for Cl(3,0)
}

__device__ __forceinline__ float clipf(float v) { return fminf(fmaxf(v, 0.f), 1.f); }

__device__ __forceinline__ unsigned short f2bf(float f) {
  unsigned u = __float_as_uint(f);
  u += 0x7FFF + ((u >> 16) & 1);           // round-to-nearest-even
  return (unsigned short)(u >> 16);
}
__device__ __forceinline__ float bf2f(unsigned short h) {
  return __uint_as_float(((unsigned)h) << 16);
}

// chunk-major tiled offset (bf16 planes): tile = 128 rows x 32 k as [4 kchunk][128 row][8 k]
__device__ __forceinline__ size_t tso128(int tr, int tk, int r, int kk) {
  return ((size_t)(tr * 64 + tk) << 12) + ((size_t)((kk >> 3) & 3) << 10) + (r << 3) + (kk & 7);
}

__device__ __forceinline__ void gload16(const void* g, void* l) {
  __builtin_amdgcn_global_load_lds((const __attribute__((address_space(1))) uint32_t*)g,
                                   (__attribute__((address_space(3))) uint32_t*)l, 16, 0, 0);
}

// scale from stored max: s = 2^(ilogb(max)+2) -> |x|*128/s < 64, digits fit in [-64,64]
__device__ __forceinline__ float dig_inv(float mx) {
  return exp2f((float)(5 - ilogbf(mx)));   // 128/s = 2^(7-(ilogb+2))
}

// ---- MRT split build: B^T [4096][2048] -> chunk-major tiled hi/lo bf16 ----
__global__ void k_build_mrt_split(const float* __restrict__ Wrec,
                                  unsigned short* __restrict__ Mhi,
                                  unsigned short* __restrict__ Mlo) {
  int idx = blockIdx.x * blockDim.x + threadIdx.x;
  int k = idx & (KDIM - 1);
  int n = idx >> 11;
  int h = k >> 3, i = k & 7;
  float v;
  if (n < KDIM) {
    int g = n >> 3, kb = n & 7;
    int j = i ^ kb;
    v = Wrec[(size_t)g * KDIM + h * NB + j] * cl3_sign(i, j);
  } else {
    int c = n - KDIM;
    int p = c >> 3, q = c & 7;
    int j = q ^ i;
    v = cl3_sign(i, i) * cl3_sign(q, j) * Wrec[(size_t)h * KDIM + p * NB + j];
  }
  unsigned short hi = f2bf(v);
  unsigned short lo = f2bf(v - bf2f(hi));
  size_t off = tso128(n >> 7, k >> 5, n & 127, k & 31);
  Mhi[off] = hi; Mlo[off] = lo;
}

// ---- global absmax of Wout -> scales[1] ----
__global__ __launch_bounds__(256) void k_wout_max(const float* __restrict__ W, float* __restrict__ scl) {
  __shared__ float red[256];
  const int t = threadIdx.x;
  size_t stride = (size_t)gridDim.x * 256;
  float m = 0.f;
  for (size_t i = (size_t)blockIdx.x * 256 + t; i < (size_t)VOCAB * KDIM / 4; i += stride) {
    float4 v = ((const float4*)W)[i];
    m = fmaxf(m, fmaxf(fmaxf(fabsf(v.x), fabsf(v.y)), fmaxf(fabsf(v.z), fabsf(v.w))));
  }
  red[t] = m; __syncthreads();
  for (int s = 128; s; s >>= 1) { if (t < s) red[t] = fmaxf(red[t], red[t + s]); __syncthreads(); }
  if (t == 0) atomicMax((unsigned*)(scl + 1), __float_as_uint(red[0]));
}

// ---- Wout digitizer: one block = one 128x32 tile -> i8 planes [2 kh16][128 row][16] ----
__global__ __launch_bounds__(256) void k_dig_wout(const float* __restrict__ W,
                                                  const float* __restrict__ scl,
                                                  char* __restrict__ Wd1,
                                                  char* __restrict__ Wd2) {
  const int tile = blockIdx.x;             // tr*64 + tk
  const int tr = tile >> 6, tk = tile & 63;
  const int t = threadIdx.x;
  const int row = t >> 1, kh = t & 1;
  const float inv = dig_inv(scl[1]);
  const float* src = W + (size_t)(tr * 128 + row) * KDIM + tk * 32 + kh * 16;
  float e[16];
#pragma unroll
  for (int q = 0; q < 4; ++q) *(float4*)&e[q * 4] = *(const float4*)(src + q * 4);
  char d1[16], d2[16];
#pragma unroll
  for (int j = 0; j < 16; ++j) {
    float tv = e[j] * inv;
    float f1 = rintf(tv);
    float f2 = rintf((tv - f1) * 128.f);
    d1[j] = (char)(int)f1; d2[j] = (char)(int)f2;
  }
  size_t off = ((size_t)tile << 12) + (kh << 11) + row * 16;
#pragma unroll
  for (int q = 0; q < 4; ++q) {
    *(int*)&Wd1[off + q * 4] = *(int*)&d1[q * 4];
    *(int*)&Wd2[off + q * 4] = *(int*)&d2[q * 4];
  }
}

// ---- A digitizer: h (raw) -> (h * bladeSign) digits, tiled i8 planes ----
__global__ __launch_bounds__(256) void k_dig_a(const float* __restrict__ Hb,
                                               const float* __restrict__ scl,
                                               char* __restrict__ Ad1,
                                               char* __restrict__ Ad2) {
  const int tile = blockIdx.x;             // tr*64 + tk, tr<8
  const int tr = tile >> 6, tk = tile & 63;
  const int t = threadIdx.x;
  const int row = t >> 1, kh = t & 1;
  const float inv = dig_inv(scl[0]);
  const float* src = Hb + (size_t)(tr * 128 + row) * KDIM + tk * 32 + kh * 16;
  float e[16];
#pragma unroll
  for (int q = 0; q < 4; ++q) *(float4*)&e[q * 4] = *(const float4*)(src + q * 4);
  char d1[16], d2[16];
#pragma unroll
  for (int j = 0; j < 16; ++j) {
    float x = e[j] * (((0xE8 >> (j & 7)) & 1) ? -1.f : 1.f);
    float tv = x * inv;
    float f1 = rintf(tv);
    float f2 = rintf((tv - f1) * 128.f);
    d1[j] = (char)(int)f1; d2[j] = (char)(int)f2;
  }
  size_t off = ((size_t)tile << 12) + (kh << 11) + row * 16;
#pragma unroll
  for (int q = 0; q < 4; ++q) {
    *(int*)&Ad1[off + q * 4] = *(int*)&d1[q * 4];
    *(int*)&Ad2[off + q * 4] = *(int*)&d2[q * 4];
  }
}

// input_mv[r][h*8+i] = sum_d emb[x[r]][d] * Win[h][d][i]; one block = 4 rows
__global__ __launch_bounds__(256) void k_input_mv(const int* __restrict__ x,
                                                  const float* __restrict__ emb,
                                                  const float* __restrict__ Win,
                                                  float* __restrict__ out) {
  __shared__ float se[4][EMB];
  int r0 = blockIdx.x * 4;
  int t = threadIdx.x;
  for (int rr = 0; rr < 4; ++rr) {
    int tok = x[r0 + rr];
    se[rr][t] = emb[(size_t)tok * EMB + t];
  }
  __syncthreads();
  float acc[4][8];
#pragma unroll
  for (int rr = 0; rr < 4; ++rr)
#pragma unroll
    for (int i = 0; i < 8; ++i) acc[rr][i] = 0.f;
  const float* wrow = Win + (size_t)t * KDIM;
  for (int d = 0; d < EMB; ++d) {
    float4 w0 = *(const float4*)(wrow + d * 8);
    float4 w1 = *(const float4*)(wrow + d * 8 + 4);
#pragma unroll
    for (int rr = 0; rr < 4; ++rr) {
      float e = se[rr][d];
      acc[rr][0] += e * w0.x; acc[rr][1] += e * w0.y;
      acc[rr][2] += e * w0.z; acc[rr][3] += e * w0.w;
      acc[rr][4] += e * w1.x; acc[rr][5] += e * w1.y;
      acc[rr][6] += e * w1.z; acc[rr][7] += e * w1.w;
    }
  }
  for (int rr = 0; rr < 4; ++rr) {
    float4* o = (float4*)(out + (size_t)(r0 + rr) * KDIM + t * 8);
    o[0] = make_float4(acc[rr][0], acc[rr][1], acc[rr][2], acc[rr][3]);
    o[1] = make_float4(acc[rr][4], acc[rr][5], acc[rr][6], acc[rr][7]);
  }
}

// ---- free-phase bf16 split GEMM, split-K x2: 512 blocks, halves -> RF0 / RF1 ----
__global__ __launch_bounds__(256, 2) void k_gemm_pre(const unsigned short* __restrict__ Ahi,
                                                     const unsigned short* __restrict__ Alo,
                                                     const unsigned short* __restrict__ Bhi,
                                                     const unsigned short* __restrict__ Blo,
                                                     float* __restrict__ RF0,
                                                     float* __restrict__ RF1) {
  __shared__ __align__(16) unsigned short lds[2][4][4096];
  const int b = blockIdx.x;                 // 512 blocks
  const int lin = (b & 7) * 64 + (b >> 3);  // XCD-chunked swizzle
  const int half = lin >> 8;
  const int inner = lin & 255;
  const int tn = inner >> 3, tm = inner & 7;
  const int ktbase = half << 5;
  float* __restrict__ C = half ? RF1 : RF0;
  const int t = threadIdx.x;
  const int l = t & 63, w = t >> 6;
  const int wr = w >> 1, wc = w & 1;

  const unsigned short* aH = Ahi + ((size_t)tm * 64 << 12);
  const unsigned short* aL = Alo + ((size_t)tm * 64 << 12);
  const unsigned short* bH = Bhi + ((size_t)tn * 64 << 12);
  const unsigned short* bL = Blo + ((size_t)tn * 64 << 12);

  const int ldso0 = w * 1024;
  const int ldso1 = ldso0 + 512;
  const int srco0 = ldso0 + (l << 3);
  const int srco1 = ldso1 + (l << 3);

  const int rA0 = wr * 64 + (l & 31);
  const int rB0 = wc * 64 + (l & 31);
  const int ch0 = l >> 5;

  f32x16 acc[2][2];
#pragma unroll
  for (int i = 0; i < 2; ++i)
#pragma unroll
    for (int j = 0; j < 2; ++j) acc[i][j] = (f32x16)0.f;

  auto STAGE = [&](int bf, int kt) {
    size_t kb = (size_t)kt << 12;
    gload16(aH + kb + srco0, &lds[bf][0][ldso0]);
    gload16(aH + kb + srco1, &lds[bf][0][ldso1]);
    gload16(aL + kb + srco0, &lds[bf][1][ldso0]);
    gload16(aL + kb + srco1, &lds[bf][1][ldso1]);
    gload16(bH + kb + srco0, &lds[bf][2][ldso0]);
    gload16(bH + kb + srco1, &lds[bf][2][ldso1]);
    gload16(bL + kb + srco0, &lds[bf][3][ldso0]);
    gload16(bL + kb + srco1, &lds[bf][3][ldso1]);
  };

  STAGE(0, ktbase);
  __syncthreads();
  int cur = 0;
  for (int it = 0; it < 32; ++it) {
    if (it < 31) STAGE(cur ^ 1, ktbase + it + 1);
#pragma unroll
    for (int s = 0; s < 2; ++s) {
      const int cb = (s * 2 + ch0) << 10;
      short8 ah[2], al[2], bh[2], bl[2];
#pragma unroll
      for (int mi = 0; mi < 2; ++mi) {
        ah[mi] = *(const short8*)&lds[cur][0][cb + ((rA0 + mi * 32) << 3)];
        al[mi] = *(const short8*)&lds[cur][1][cb + ((rA0 + mi * 32) << 3)];
      }
#pragma unroll
      for (int nj = 0; nj < 2; ++nj) {
        bh[nj] = *(const short8*)&lds[cur][2][cb + ((rB0 + nj * 32) << 3)];
        bl[nj] = *(const short8*)&lds[cur][3][cb + ((rB0 + nj * 32) << 3)];
      }
#pragma unroll
      for (int mi = 0; mi < 2; ++mi)
#pragma unroll
        for (int nj = 0; nj < 2; ++nj) {
          acc[mi][nj] = __builtin_amdgcn_mfma_f32_32x32x16_bf16(ah[mi], bh[nj], acc[mi][nj], 0, 0, 0);
          acc[mi][nj] = __builtin_amdgcn_mfma_f32_32x32x16_bf16(ah[mi], bl[nj], acc[mi][nj], 0, 0, 0);
          acc[mi][nj] = __builtin_amdgcn_mfma_f32_32x32x16_bf16(al[mi], bh[nj], acc[mi][nj], 0, 0, 0);
        }
    }
    __syncthreads();
    cur ^= 1;
  }

  const int rg0 = tm * 128 + wr * 64 + ((l >> 5) << 2);
  const int cg0 = tn * 128 + wc * 64 + (l & 31);
#pragma unroll
  for (int mi = 0; mi < 2; ++mi)
#pragma unroll
    for (int nj = 0; nj < 2; ++nj) {
      f32x16 v = acc[mi][nj];
#pragma unroll
      for (int g = 0; g < 16; ++g) {
        int rr = (g & 3) + ((g >> 2) << 3);
        C[(size_t)(rg0 + mi * 32 + rr) * NCOL + cg0 + nj * 32] = v[g];
      }
    }
}

// ---- i8 digit GEMM (logits): C = sA*sB/16384 * (acc1 + acc2/128) ----
__global__ __launch_bounds__(256, 2) void k_gemm_i8(const char* __restrict__ Ad1,
                                                    const char* __restrict__ Ad2,
                                                    const char* __restrict__ Bd1,
                                                    const char* __restrict__ Bd2,
                                                    const float* __restrict__ scl,
                                                    float* __restrict__ C) {
  __shared__ __align__(16) char lds[2][4][4096];
  const int nwg = gridDim.x;                        // 2000
  const int b = blockIdx.x;
  const int lin = (b & 7) * (nwg >> 3) + (b >> 3);  // XCD-chunked swizzle
  const int tn = lin >> 3, tm = lin & 7;
  const int t = threadIdx.x;
  const int l = t & 63, w = t >> 6;
  const int wr = w >> 1, wc = w & 1;

  const char* psrc;
  {
    size_t ao = (size_t)tm * 64 << 12, bo = (size_t)tn * 64 << 12;
    psrc = (w == 0) ? Ad1 + ao : (w == 1) ? Ad2 + ao : (w == 2) ? Bd1 + bo : Bd2 + bo;
  }

  const int kh = (l >> 5) << 11;                    // byte offset of k-half plane
  const int rA = wr * 64 + (l & 31);
  const int rB = wc * 64 + (l & 31);

  i32x16 acc1[2][2], acc2[2][2];
#pragma unroll
  for (int i = 0; i < 2; ++i)
#pragma unroll
    for (int j = 0; j < 2; ++j) { acc1[i][j] = (i32x16)0; acc2[i][j] = (i32x16)0; }

  auto STAGE = [&](int bf, int kt) {
    const char* s = psrc + ((size_t)kt << 12) + l * 16;
    char* d = &lds[bf][w][0];
    gload16(s, d);
    gload16(s + 1024, d + 1024);
    gload16(s + 2048, d + 2048);
    gload16(s + 3072, d + 3072);
  };

  STAGE(0, 0);
  __syncthreads();
  int cur = 0;
  for (int kt = 0; kt < 64; ++kt) {
    if (kt < 63) STAGE(cur ^ 1, kt + 1);
    i32x4 a1[2], a2[2], b1[2], b2[2];
#pragma unroll
    for (int mi = 0; mi < 2; ++mi) {
      int off = kh + (rA + mi * 32) * 16;
      a1[mi] = *(const i32x4*)&lds[cur][0][off];
      a2[mi] = *(const i32x4*)&lds[cur][1][off];
    }
#pragma unroll
    for (int nj = 0; nj < 2; ++nj) {
      int off = kh + (rB + nj * 32) * 16;
      b1[nj] = *(const i32x4*)&lds[cur][2][off];
      b2[nj] = *(const i32x4*)&lds[cur][3][off];
    }
#pragma unroll
    for (int mi = 0; mi < 2; ++mi)
#pragma unroll
      for (int nj = 0; nj < 2; ++nj) {
        acc1[mi][nj] = __builtin_amdgcn_mfma_i32_32x32x32_i8(a1[mi], b1[nj], acc1[mi][nj], 0, 0, 0);
        acc2[mi][nj] = __builtin_amdgcn_mfma_i32_32x32x32_i8(a1[mi], b2[nj], acc2[mi][nj], 0, 0, 0);
        acc2[mi][nj] = __builtin_amdgcn_mfma_i32_32x32x32_i8(a2[mi], b1[nj], acc2[mi][nj], 0, 0, 0);
      }
    __syncthreads();
    cur ^= 1;
  }

  const float sA = exp2f((float)(ilogbf(scl[0]) + 2));
  const float sB = exp2f((float)(ilogbf(scl[1]) + 2));
  const float c1 = sA * sB * (1.f / 16384.f);
  const float c2 = c1 * (1.f / 128.f);

  const int rg0 = tm * 128 + wr * 64 + ((l >> 5) << 2);
  const int cg0 = tn * 128 + wc * 64 + (l & 31);
#pragma unroll
  for (int mi = 0; mi < 2; ++mi)
#pragma unroll
    for (int nj = 0; nj < 2; ++nj) {
#pragma unroll
      for (int g = 0; g < 16; ++g) {
        int rr = (g & 3) + ((g >> 2) << 3);
        C[(size_t)(rg0 + mi * 32 + rr) * VOCAB + cg0 + nj * 32] =
            fmaf((float)acc2[mi][nj][g], c2, (float)acc1[mi][nj][g] * c1);
      }
    }
}

// h <- h - 0.1*(h - drho(h)*(inmv*sq + rec_prev*sq + fwd_next)); RF = RF0+RF1 (split-K)
template <int LAST>
__global__ __launch_bounds__(256) void k_update(float* __restrict__ Hb, const float* __restrict__ Imv,
                                                const float* __restrict__ RF0, const float* __restrict__ RF1,
                                                unsigned short* __restrict__ Hhi,
                                                unsigned short* __restrict__ Hlo,
                                                float* __restrict__ scl) {
  __shared__ float red[256];
  int tix = threadIdx.x;
  int idx = blockIdx.x * 256 + tix;
  int r = idx >> 8;
  int c = (idx & 255) << 3;
  int m = r & (LLEN - 1);
  const size_t base = (size_t)r * KDIM + c;
  float h[8], f[8];
  *(float4*)&h[0] = *(const float4*)(Hb + base);
  *(float4*)&h[4] = *(const float4*)(Hb + base + 4);
  float4 i0 = *(const float4*)(Imv + base);
  float4 i1 = *(const float4*)(Imv + base + 4);
  f[0] = i0.x; f[1] = i0.y; f[2] = i0.z; f[3] = i0.w;
  f[4] = i1.x; f[5] = i1.y; f[6] = i1.z; f[7] = i1.w;
#pragma unroll
  for (int j = 0; j < 8; ++j) f[j] *= ((0xE8 >> j) & 1) ? -1.f : 1.f;
  if (m >= 1) {
    const float* rp0 = RF0 + (size_t)(r - 1) * NCOL + c;
    const float* rp1 = RF1 + (size_t)(r - 1) * NCOL + c;
#pragma unroll
    for (int j = 0; j < 8; ++j)
      f[j] += (rp0[j] + rp1[j]) * (((0xE8 >> j) & 1) ? -1.f : 1.f);
  }
  if (m < LLEN - 1) {
    const float* rn0 = RF0 + (size_t)(r + 1) * NCOL + KDIM + c;
    const float* rn1 = RF1 + (size_t)(r + 1) * NCOL + KDIM + c;
#pragma unroll
    for (int j = 0; j < 8; ++j) f[j] += rn0[j] + rn1[j];
  }
  float hn[8];
  float lm = 0.f;
  short8 h8, l8;
#pragma unroll
  for (int j = 0; j < 8; ++j) {
    float hv = h[j];
    float dr = (hv > 0.f && hv < 1.f) ? 1.f : ((hv == 0.f || hv == 1.f) ? 0.5f : 0.f);
    hn[j] = hv - 0.1f * (hv - dr * f[j]);
    if (LAST) {
      lm = fmaxf(lm, fabsf(hn[j]));
    } else {
      float av = clipf(hn[j]);
      unsigned short hi = f2bf(av);
      h8[j] = (short)hi;
      l8[j] = (short)f2bf(av - bf2f(hi));
    }
  }
  *(float4*)(Hb + base) = make_float4(hn[0], hn[1], hn[2], hn[3]);
  *(float4*)(Hb + base + 4) = make_float4(hn[4], hn[5], hn[6], hn[7]);
  if (LAST) {
    red[tix] = lm; __syncthreads();
    for (int s = 128; s; s >>= 1) { if (tix < s) red[tix] = fmaxf(red[tix], red[tix + s]); __syncthreads(); }
    if (tix == 0) atomicMax((unsigned*)scl, __float_as_uint(red[0]));
  } else {
    size_t off = tso128(r >> 7, c >> 5, r & 127, c & 31);
    *(short8*)&Hhi[off] = h8;
    *(short8*)&Hlo[off] = l8;
  }
}

// ---- fallback logits GEMM (in-kernel bf16 conversion), used if ws too small ----
template <int AMODE>
__global__ __launch_bounds__(256) void k_gemm_split(const float* __restrict__ A,
                                                    const float* __restrict__ B,
                                                    float* __restrict__ C, int ldc) {
  __shared__ unsigned short Ah[128 * 32], Al[128 * 32];
  __shared__ unsigned short Bh[128 * 32], Bl[128 * 32];
  const int t = threadIdx.x;
  const int row0 = blockIdx.y * 128, col0 = blockIdx.x * 128;
  const int l = t & 63, w = t >> 6;
  const int wr = w >> 1, wc = w & 1;
  const int sr = t >> 3;
  const int cc = (t & 7) << 2;
  const int chunkb = cc >> 3;
  const int halfo = (cc >> 2) & 1;
  f32x4 acc[4][4];
#pragma unroll
  for (int i = 0; i < 4; ++i)
#pragma unroll
    for (int j = 0; j < 4; ++j) acc[i][j] = (f32x4)0.f;
  const float sA0 = 1.f;
  const float sA1 = (cc & 4) ? -1.f : 1.f;
  const float sA2 = sA1;
  const float sA3 = -1.f;
  for (int k0 = 0; k0 < KDIM; k0 += 32) {
    float4 va[4], vb[4];
#pragma unroll
    for (int i = 0; i < 4; ++i) {
      va[i] = *(const float4*)(A + (size_t)(row0 + sr + i * 32) * KDIM + k0 + cc);
      vb[i] = *(const float4*)(B + (size_t)(col0 + sr + i * 32) * KDIM + k0 + cc);
    }
    __syncthreads();
#pragma unroll
    for (int i = 0; i < 4; ++i) {
      int row = sr + i * 32;
      int idx = row * 32 + ((chunkb ^ (row & 3)) << 3) + (halfo << 2);
      float4 a = va[i];
      if (AMODE == 0) {
        a.x = clipf(a.x); a.y = clipf(a.y); a.z = clipf(a.z); a.w = clipf(a.w);
      } else {
        a.x *= sA0; a.y *= sA1; a.z *= sA2; a.w *= sA3;
      }
      ushort4 h4, l4;
      h4.x = f2bf(a.x); l4.x = f2bf(a.x - bf2f(h4.x));
      h4.y = f2bf(a.y); l4.y = f2bf(a.y - bf2f(h4.y));
      h4.z = f2bf(a.z); l4.z = f2bf(a.z - bf2f(h4.z));
      h4.w = f2bf(a.w); l4.w = f2bf(a.w - bf2f(h4.w));
      *(ushort4*)&Ah[idx] = h4;
      *(ushort4*)&Al[idx] = l4;
      float4 bb = vb[i];
      h4.x = f2bf(bb.x); l4.x = f2bf(bb.x - bf2f(h4.x));
      h4.y = f2bf(bb.y); l4.y = f2bf(bb.y - bf2f(h4.y));
      h4.z = f2bf(bb.z); l4.z = f2bf(bb.z - bf2f(h4.z));
      h4.w = f2bf(bb.w); l4.w = f2bf(bb.w - bf2f(h4.w));
      *(ushort4*)&Bh[idx] = h4;
      *(ushort4*)&Bl[idx] = l4;
    }
    __syncthreads();
    short8 ah[4], al[4], bh[4], bl[4];
#pragma unroll
    for (int mi = 0; mi < 4; ++mi) {
      int ar = wr * 64 + mi * 16 + (l & 15);
      int kc = (l >> 4) ^ (ar & 3);
      ah[mi] = *(short8*)&Ah[ar * 32 + kc * 8];
      al[mi] = *(short8*)&Al[ar * 32 + kc * 8];
      int br = wc * 64 + mi * 16 + (l & 15);
      int kb = (l >> 4) ^ (br & 3);
      bh[mi] = *(short8*)&Bh[br * 32 + kb * 8];
      bl[mi] = *(short8*)&Bl[br * 32 + kb * 8];
    }
#pragma unroll
    for (int mi = 0; mi < 4; ++mi)
#pragma unroll
      for (int ni = 0; ni < 4; ++ni) {
        acc[mi][ni] = __builtin_amdgcn_mfma_f32_16x16x32_bf16(ah[mi], bh[ni], acc[mi][ni], 0, 0, 0);
        acc[mi][ni] = __builtin_amdgcn_mfma_f32_16x16x32_bf16(ah[mi], bl[ni], acc[mi][ni], 0, 0, 0);
        acc[mi][ni] = __builtin_amdgcn_mfma_f32_16x16x32_bf16(al[mi], bh[ni], acc[mi][ni], 0, 0, 0);
      }
  }
#pragma unroll
  for (int mi = 0; mi < 4; ++mi)
#pragma unroll
    for (int ni = 0; ni < 4; ++ni) {
      int rg = row0 + wr * 64 + mi * 16 + (l >> 4) * 4;
      int cg = col0 + wc * 64 + ni * 16 + (l & 15);
#pragma unroll
      for (int j = 0; j < 4; ++j)
        C[(size_t)(rg + j) * ldc + cg] = acc[mi][ni][j];
    }
}

extern "C" void kernel_launch(void* const* d_in, const int* in_sizes, int n_in,
                              void* d_out, int out_size, void* d_ws, size_t ws_size,
                              hipStream_t stream) {
  const int*   x    = (const int*)d_in[0];
  const float* emb  = (const float*)d_in[1];
  const float* Win  = (const float*)d_in[2];
  const float* Wrec = (const float*)d_in[3];
  const float* Wout = (const float*)d_in[4];
  float* logits = (float*)d_out;

  char* base = (char*)d_ws;
  const size_t MB = 1ull << 20;
  float* Hbuf = (float*)(base + 0);
  float* Imv  = (float*)(base + 8 * MB);
  float* RF0  = (float*)(base + 16 * MB);
  float* RF1  = (float*)(base + 32 * MB);
  unsigned short* Hhi = (unsigned short*)(base + 48 * MB);
  unsigned short* Hlo = (unsigned short*)(base + 52 * MB);
  unsigned short* Mhi = (unsigned short*)(base + 56 * MB);
  unsigned short* Mlo = (unsigned short*)(base + 72 * MB);
  float* scl = (float*)(base + 88 * MB);
  char* Ad1  = base + 88 * MB + 4096;
  char* Ad2  = Ad1 + 2 * MB;
  char* Wd1  = Ad2 + 2 * MB;
  char* Wd2  = Wd1 + (size_t)VOCAB * KDIM;

  const size_t need = (size_t)(Wd2 - base) + (size_t)VOCAB * KDIM;
  const bool big = ws_size >= need;

  hipMemsetAsync(Hbuf, 0, 8 * MB, stream);
  hipMemsetAsync(Hhi, 0, 8 * MB, stream);          // Hhi+Hlo contiguous
  if (big) hipMemsetAsync(scl, 0, 16, stream);
  k_build_mrt_split<<<32768, 256, 0, stream>>>(Wrec, Mhi, Mlo);
  k_input_mv<<<256, 256, 0, stream>>>(x, emb, Win, Imv);
  if (big) {
    k_wout_max<<<2048, 256, 0, stream>>>(Wout, scl);
    k_dig_wout<<<16000, 256, 0, stream>>>(Wout, scl, Wd1, Wd2);
  }

  for (int it = 0; it < 5; ++it) {
    k_gemm_pre<<<512, 256, 0, stream>>>(Hhi, Hlo, Mhi, Mlo, RF0, RF1);
    if (it < 4) k_update<0><<<1024, 256, 0, stream>>>(Hbuf, Imv, RF0, RF1, Hhi, Hlo, scl);
    else        k_update<1><<<1024, 256, 0, stream>>>(Hbuf, Imv, RF0, RF1, Hhi, Hlo, scl);
  }

  if (big) {
    k_dig_a<<<512, 256, 0, stream>>>(Hbuf, scl, Ad1, Ad2);
    k_gemm_i8<<<2000, 256, 0, stream>>>(Ad1, Ad2, Wd1, Wd2, scl, logits);
  } else {
    k_gemm_split<1><<<dim3(VOCAB / 128, NROWS / 128), 256, 0, stream>>>(Hbuf, Wout, logits, VOCAB);
  }
}

// Round 6
// 750.529 us; speedup vs baseline: 1.2130x; 1.0693x over previous
//
#include <hip/hip_runtime.h>
#include <cstddef>
#include <cstdint>

#define VOCAB  32000
#define EMB    256
#define NB     8
#define KDIM   2048        /* H*NB */
#define NROWS  1024        /* B*L  */
#define NCOL   4096        /* 2*KDIM */
#define LLEN   256

typedef __attribute__((ext_vector_type(8))) short short8;
typedef __attribute__((ext_vector_type(4))) float f32x4;
typedef __attribute__((ext_vector_type(16))) float f32x16;
typedef __attribute__((ext_vector_type(4))) int i32x4;
typedef __attribute__((ext_vector_type(16))) int i32x16;

__device__ __forceinline__ float cl3_sign(int a, int b) {
  int x = a >> 1, p = 0;
  while (x) { p ^= __popc(x & b) & 1; x >>= 1; }
  return p ? -1.f : 1.f;   // metric all +1 for Cl(3,0)
}

__device__ __forceinline__ float clipf(float v) { return fminf(fmaxf(v, 0.f), 1.f); }

__device__ __forceinline__ unsigned short f2bf(float f) {
  unsigned u = __float_as_uint(f);
  u += 0x7FFF + ((u >> 16) & 1);           // round-to-nearest-even
  return (unsigned short)(u >> 16);
}
__device__ __forceinline__ float bf2f(unsigned short h) {
  return __uint_as_float(((unsigned)h) << 16);
}

// chunk-major tiled offset (bf16 planes, free phase): tile = 128 rows x 32 k as [4 kchunk][128 row][8 k]
__device__ __forceinline__ size_t tso128(int tr, int tk, int r, int kk) {
  return ((size_t)(tr * 64 + tk) << 12) + ((size_t)((kk >> 3) & 3) << 10) + (r << 3) + (kk & 7);
}

__device__ __forceinline__ void gload16(const void* g, void* l) {
  __builtin_amdgcn_global_load_lds((const __attribute__((address_space(1))) uint32_t*)g,
                                   (__attribute__((address_space(3))) uint32_t*)l, 16, 0, 0);
}

// scale: s = 2^(ilogb(max)+2); inv = 128/s; digits in [-64,64]
__device__ __forceinline__ float dig_inv(float mx) {
  return exp2f((float)(5 - ilogbf(fmaxf(mx, 1e-20f))));
}

// ---- MRT split build: B^T [4096][2048] -> chunk-major tiled hi/lo bf16 ----
__global__ void k_build_mrt_split(const float* __restrict__ Wrec,
                                  unsigned short* __restrict__ Mhi,
                                  unsigned short* __restrict__ Mlo) {
  int idx = blockIdx.x * blockDim.x + threadIdx.x;
  int k = idx & (KDIM - 1);
  int n = idx >> 11;
  int h = k >> 3, i = k & 7;
  float v;
  if (n < KDIM) {
    int g = n >> 3, kb = n & 7;
    int j = i ^ kb;
    v = Wrec[(size_t)g * KDIM + h * NB + j] * cl3_sign(i, j);
  } else {
    int c = n - KDIM;
    int p = c >> 3, q = c & 7;
    int j = q ^ i;
    v = cl3_sign(i, i) * cl3_sign(q, j) * Wrec[(size_t)h * KDIM + p * NB + j];
  }
  unsigned short hi = f2bf(v);
  unsigned short lo = f2bf(v - bf2f(hi));
  size_t off = tso128(n >> 7, k >> 5, n & 127, k & 31);
  Mhi[off] = hi; Mlo[off] = lo;
}

// ---- global absmax of Wout -> scl[1] ----
__global__ __launch_bounds__(256) void k_wout_max(const float* __restrict__ W, float* __restrict__ scl) {
  __shared__ float red[256];
  const int t = threadIdx.x;
  size_t stride = (size_t)gridDim.x * 256;
  float m = 0.f;
  for (size_t i = (size_t)blockIdx.x * 256 + t; i < (size_t)VOCAB * KDIM / 4; i += stride) {
    float4 v = ((const float4*)W)[i];
    m = fmaxf(m, fmaxf(fmaxf(fabsf(v.x), fabsf(v.y)), fmaxf(fabsf(v.z), fabsf(v.w))));
  }
  red[t] = m; __syncthreads();
  for (int s = 128; s; s >>= 1) { if (t < s) red[t] = fmaxf(red[t], red[t + s]); __syncthreads(); }
  if (t == 0) atomicMax((unsigned*)(scl + 1), __float_as_uint(red[0]));
}

// ---- Wout digitizer: one block = one [256 v-rows x 64 k] slab -> i8 planes [4 kq][256 row][16] ----
__global__ __launch_bounds__(256) void k_dig_wout(const float* __restrict__ W,
                                                  const float* __restrict__ scl,
                                                  char* __restrict__ Wd1,
                                                  char* __restrict__ Wd2) {
  __shared__ char l1[16384], l2[16384];
  const int tn = blockIdx.x >> 5;          // 125 n-tiles
  const int kt = blockIdx.x & 31;          // 32 k-tiles
  const int t = threadIdx.x;
  const float inv = dig_inv(scl[1]);
#pragma unroll
  for (int p = 0; p < 8; ++p) {
    int ci = p * 256 + t;                  // 0..2047 chunk of 8 floats
    int row = ci >> 3, koff = (ci & 7) * 8;
    const float* src = W + (size_t)(tn * 256 + row) * KDIM + kt * 64 + koff;
    float e[8];
    *(float4*)&e[0] = *(const float4*)src;
    *(float4*)&e[4] = *(const float4*)(src + 4);
    char d1[8], d2[8];
#pragma unroll
    for (int j = 0; j < 8; ++j) {
      float tv = e[j] * inv;
      float f1 = rintf(tv);
      d1[j] = (char)(int)f1;
      d2[j] = (char)(int)rintf((tv - f1) * 128.f);
    }
    int lo = ((koff >> 4) << 12) + (row << 4) + (koff & 8);
    *(uint64_t*)&l1[lo] = *(uint64_t*)d1;
    *(uint64_t*)&l2[lo] = *(uint64_t*)d2;
  }
  __syncthreads();
  size_t ob = ((size_t)blockIdx.x << 14) + t * 64;
#pragma unroll
  for (int q = 0; q < 4; ++q) {
    *(i32x4*)&Wd1[ob + q * 16] = *(const i32x4*)&l1[t * 64 + q * 16];
    *(i32x4*)&Wd2[ob + q * 16] = *(const i32x4*)&l2[t * 64 + q * 16];
  }
}

// input_mv[r][h*8+i] = sum_d emb[x[r]][d] * Win[h][d][i]; one block = 4 rows
__global__ __launch_bounds__(256) void k_input_mv(const int* __restrict__ x,
                                                  const float* __restrict__ emb,
                                                  const float* __restrict__ Win,
                                                  float* __restrict__ out) {
  __shared__ float se[4][EMB];
  int r0 = blockIdx.x * 4;
  int t = threadIdx.x;
  for (int rr = 0; rr < 4; ++rr) {
    int tok = x[r0 + rr];
    se[rr][t] = emb[(size_t)tok * EMB + t];
  }
  __syncthreads();
  float acc[4][8];
#pragma unroll
  for (int rr = 0; rr < 4; ++rr)
#pragma unroll
    for (int i = 0; i < 8; ++i) acc[rr][i] = 0.f;
  const float* wrow = Win + (size_t)t * KDIM;
  for (int d = 0; d < EMB; ++d) {
    float4 w0 = *(const float4*)(wrow + d * 8);
    float4 w1 = *(const float4*)(wrow + d * 8 + 4);
#pragma unroll
    for (int rr = 0; rr < 4; ++rr) {
      float e = se[rr][d];
      acc[rr][0] += e * w0.x; acc[rr][1] += e * w0.y;
      acc[rr][2] += e * w0.z; acc[rr][3] += e * w0.w;
      acc[rr][4] += e * w1.x; acc[rr][5] += e * w1.y;
      acc[rr][6] += e * w1.z; acc[rr][7] += e * w1.w;
    }
  }
  for (int rr = 0; rr < 4; ++rr) {
    float4* o = (float4*)(out + (size_t)(r0 + rr) * KDIM + t * 8);
    o[0] = make_float4(acc[rr][0], acc[rr][1], acc[rr][2], acc[rr][3]);
    o[1] = make_float4(acc[rr][4], acc[rr][5], acc[rr][6], acc[rr][7]);
  }
}

// ---- free-phase bf16 split GEMM, split-K x2 (unchanged: bit-identical trajectory) ----
__global__ __launch_bounds__(256, 2) void k_gemm_pre(const unsigned short* __restrict__ Ahi,
                                                     const unsigned short* __restrict__ Alo,
                                                     const unsigned short* __restrict__ Bhi,
                                                     const unsigned short* __restrict__ Blo,
                                                     float* __restrict__ RF0,
                                                     float* __restrict__ RF1) {
  __shared__ __align__(16) unsigned short lds[2][4][4096];
  const int b = blockIdx.x;                 // 512 blocks
  const int lin = (b & 7) * 64 + (b >> 3);  // XCD-chunked swizzle
  const int half = lin >> 8;
  const int inner = lin & 255;
  const int tn = inner >> 3, tm = inner & 7;
  const int ktbase = half << 5;
  float* __restrict__ C = half ? RF1 : RF0;
  const int t = threadIdx.x;
  const int l = t & 63, w = t >> 6;
  const int wr = w >> 1, wc = w & 1;

  const unsigned short* aH = Ahi + ((size_t)tm * 64 << 12);
  const unsigned short* aL = Alo + ((size_t)tm * 64 << 12);
  const unsigned short* bH = Bhi + ((size_t)tn * 64 << 12);
  const unsigned short* bL = Blo + ((size_t)tn * 64 << 12);

  const int ldso0 = w * 1024;
  const int ldso1 = ldso0 + 512;
  const int srco0 = ldso0 + (l << 3);
  const int srco1 = ldso1 + (l << 3);

  const int rA0 = wr * 64 + (l & 31);
  const int rB0 = wc * 64 + (l & 31);
  const int ch0 = l >> 5;

  f32x16 acc[2][2];
#pragma unroll
  for (int i = 0; i < 2; ++i)
#pragma unroll
    for (int j = 0; j < 2; ++j) acc[i][j] = (f32x16)0.f;

  auto STAGE = [&](int bf, int kt) {
    size_t kb = (size_t)kt << 12;
    gload16(aH + kb + srco0, &lds[bf][0][ldso0]);
    gload16(aH + kb + srco1, &lds[bf][0][ldso1]);
    gload16(aL + kb + srco0, &lds[bf][1][ldso0]);
    gload16(aL + kb + srco1, &lds[bf][1][ldso1]);
    gload16(bH + kb + srco0, &lds[bf][2][ldso0]);
    gload16(bH + kb + srco1, &lds[bf][2][ldso1]);
    gload16(bL + kb + srco0, &lds[bf][3][ldso0]);
    gload16(bL + kb + srco1, &lds[bf][3][ldso1]);
  };

  STAGE(0, ktbase);
  __syncthreads();
  int cur = 0;
  for (int it = 0; it < 32; ++it) {
    if (it < 31) STAGE(cur ^ 1, ktbase + it + 1);
#pragma unroll
    for (int s = 0; s < 2; ++s) {
      const int cb = (s * 2 + ch0) << 10;
      short8 ah[2], al[2], bh[2], bl[2];
#pragma unroll
      for (int mi = 0; mi < 2; ++mi) {
        ah[mi] = *(const short8*)&lds[cur][0][cb + ((rA0 + mi * 32) << 3)];
        al[mi] = *(const short8*)&lds[cur][1][cb + ((rA0 + mi * 32) << 3)];
      }
#pragma unroll
      for (int nj = 0; nj < 2; ++nj) {
        bh[nj] = *(const short8*)&lds[cur][2][cb + ((rB0 + nj * 32) << 3)];
        bl[nj] = *(const short8*)&lds[cur][3][cb + ((rB0 + nj * 32) << 3)];
      }
#pragma unroll
      for (int mi = 0; mi < 2; ++mi)
#pragma unroll
        for (int nj = 0; nj < 2; ++nj) {
          acc[mi][nj] = __builtin_amdgcn_mfma_f32_32x32x16_bf16(ah[mi], bh[nj], acc[mi][nj], 0, 0, 0);
          acc[mi][nj] = __builtin_amdgcn_mfma_f32_32x32x16_bf16(ah[mi], bl[nj], acc[mi][nj], 0, 0, 0);
          acc[mi][nj] = __builtin_amdgcn_mfma_f32_32x32x16_bf16(al[mi], bh[nj], acc[mi][nj], 0, 0, 0);
        }
    }
    __syncthreads();
    cur ^= 1;
  }

  const int rg0 = tm * 128 + wr * 64 + ((l >> 5) << 2);
  const int cg0 = tn * 128 + wc * 64 + (l & 31);
#pragma unroll
  for (int mi = 0; mi < 2; ++mi)
#pragma unroll
    for (int nj = 0; nj < 2; ++nj) {
      f32x16 v = acc[mi][nj];
#pragma unroll
      for (int g = 0; g < 16; ++g) {
        int rr = (g & 3) + ((g >> 2) << 3);
        C[(size_t)(rg0 + mi * 32 + rr) * NCOL + cg0 + nj * 32] = v[g];
      }
    }
}

// ---- i8 digit GEMM (logits), counted-vmcnt 3-buffer pipeline ----
// tile 128x256, 8 waves (2M x 4N, 64x64 each), BK=64, 1 raw barrier per K-tile.
__global__ __launch_bounds__(512, 1) void k_gemm_i8(const char* __restrict__ Ad1,
                                                    const char* __restrict__ Ad2,
                                                    const char* __restrict__ Bd1,
                                                    const char* __restrict__ Bd2,
                                                    const float* __restrict__ scl,
                                                    const float* __restrict__ sA,
                                                    float* __restrict__ C) {
  __shared__ __align__(16) char lds[3 * 49152];   // 3 x {A1 8K | A2 8K | B1 16K | B2 16K}
  const int b = blockIdx.x;                       // 1000 blocks
  const int lin = (b & 7) * 125 + (b >> 3);       // XCD-chunked (1000 % 8 == 0)
  const int tm = lin & 7, tn = lin >> 3;          // 8 consecutive lin share B panel
  const int t = threadIdx.x;
  const int l = t & 63, w = t >> 6;
  const int wr = w >> 2, wc = w & 3;

  const char* a1g = Ad1 + ((size_t)tm * 32 << 13) + (t << 4);
  const char* a2g = Ad2 + ((size_t)tm * 32 << 13) + (t << 4);
  const char* b1g = Bd1 + ((size_t)tn * 32 << 14) + (t << 4);
  const char* b2g = Bd2 + ((size_t)tn * 32 << 14) + (t << 4);
  const int wub = w << 10;                        // wave-uniform LDS dest

  // frag byte offsets within a buffer, per k-step s: kq = s*2 + (l>>5)
  const int la = (l & 31) << 4;
  const int rowa0 = (wr * 64 + 0) << 4, rowa1 = (wr * 64 + 32) << 4;
  const int rowb0 = (wc * 64 + 0) << 4, rowb1 = (wc * 64 + 32) << 4;
  const int kqh = (l >> 5) << 1;                  // 0 or 2 (x2048 for A, x4096 for B)

  i32x16 acc1[2][2], acc2[2][2];
#pragma unroll
  for (int i = 0; i < 2; ++i)
#pragma unroll
    for (int j = 0; j < 2; ++j) { acc1[i][j] = (i32x16)0; acc2[i][j] = (i32x16)0; }

  auto STAGE_H = [&](int bf, int kt, int h) {
    char* lb = &lds[bf * 49152];
    size_t ka = (size_t)kt << 13, kb = (size_t)kt << 14;
    if (h == 0) {
      gload16(a1g + ka, lb + wub);
      gload16(a2g + ka, lb + 8192 + wub);
      gload16(b1g + kb, lb + 16384 + wub);
    } else {
      gload16(b1g + kb + 8192, lb + 24576 + wub);
      gload16(b2g + kb, lb + 32768 + wub);
      gload16(b2g + kb + 8192, lb + 40960 + wub);
    }
  };

  STAGE_H(0, 0, 0); STAGE_H(0, 0, 1);
  STAGE_H(1, 1, 0); STAGE_H(1, 1, 1);

  int cur = 0;
  for (int kt = 0; kt < 32; ++kt) {
    int pf = cur + 2; if (pf >= 3) pf -= 3;
    if (kt < 31) { asm volatile("s_waitcnt vmcnt(6)" ::: "memory"); }
    else         { asm volatile("s_waitcnt vmcnt(0)" ::: "memory"); }
    __builtin_amdgcn_s_barrier();
    const char* lb = &lds[cur * 49152];
#pragma unroll
    for (int s = 0; s < 2; ++s) {
      const int kqa = ((s << 1) + (l >> 5)) << 11;   // A plane kq offset (x2048)
      const int kqb = ((s << 1) + (l >> 5)) << 12;   // B plane kq offset (x4096)
      i32x4 a1[2], a2[2], b1[2], b2[2];
      a1[0] = *(const i32x4*)(lb + kqa + rowa0 + la);
      a1[1] = *(const i32x4*)(lb + kqa + rowa1 + la);
      a2[0] = *(const i32x4*)(lb + 8192 + kqa + rowa0 + la);
      a2[1] = *(const i32x4*)(lb + 8192 + kqa + rowa1 + la);
      b1[0] = *(const i32x4*)(lb + 16384 + kqb + rowb0 + la);
      b1[1] = *(const i32x4*)(lb + 16384 + kqb + rowb1 + la);
      b2[0] = *(const i32x4*)(lb + 32768 + kqb + rowb0 + la);
      b2[1] = *(const i32x4*)(lb + 32768 + kqb + rowb1 + la);
      if (kt + 2 < 32) STAGE_H(pf, kt + 2, s);
      __builtin_amdgcn_s_setprio(1);
#pragma unroll
      for (int mi = 0; mi < 2; ++mi)
#pragma unroll
        for (int nj = 0; nj < 2; ++nj) {
          acc1[mi][nj] = __builtin_amdgcn_mfma_i32_32x32x32_i8(a1[mi], b1[nj], acc1[mi][nj], 0, 0, 0);
          acc2[mi][nj] = __builtin_amdgcn_mfma_i32_32x32x32_i8(a1[mi], b2[nj], acc2[mi][nj], 0, 0, 0);
          acc2[mi][nj] = __builtin_amdgcn_mfma_i32_32x32x32_i8(a2[mi], b1[nj], acc2[mi][nj], 0, 0, 0);
        }
      __builtin_amdgcn_s_setprio(0);
    }
    cur = (cur == 2) ? 0 : cur + 1;
  }

  const float sB = exp2f((float)(ilogbf(scl[1]) + 2));
  const int rbase = tm * 128 + wr * 64 + ((l >> 5) << 2);
  const int cbase = tn * 256 + wc * 64 + (l & 31);
#pragma unroll
  for (int mi = 0; mi < 2; ++mi)
#pragma unroll
    for (int nj = 0; nj < 2; ++nj) {
#pragma unroll
      for (int g = 0; g < 16; ++g) {
        int rr = (g & 3) + ((g >> 2) << 3);
        int row = rbase + mi * 32 + rr;
        float c1 = sA[row] * sB * (1.f / 16384.f);
        C[(size_t)row * VOCAB + cbase + nj * 32] =
            fmaf((float)acc2[mi][nj][g], c1 * (1.f / 128.f), (float)acc1[mi][nj][g] * c1);
      }
    }
}

// h <- h - 0.1*(h - drho(h)*(inmv*sq + rec_prev*sq + fwd_next))
// LAST=0: emit bf16 hi/lo planes for next free-phase GEMM
// LAST=1: per-row scale + i8 digitization of h*bladeSign (block = one row)
template <int LAST>
__global__ __launch_bounds__(256) void k_update(float* __restrict__ Hb, const float* __restrict__ Imv,
                                                const float* __restrict__ RF0, const float* __restrict__ RF1,
                                                unsigned short* __restrict__ Hhi,
                                                unsigned short* __restrict__ Hlo,
                                                float* __restrict__ sA,
                                                char* __restrict__ Ad1,
                                                char* __restrict__ Ad2,
                                                int big) {
  __shared__ float red[256];
  int tix = threadIdx.x;
  int idx = blockIdx.x * 256 + tix;
  int r = idx >> 8;
  int c = (idx & 255) << 3;
  int m = r & (LLEN - 1);
  const size_t base = (size_t)r * KDIM + c;
  float h[8], f[8];
  *(float4*)&h[0] = *(const float4*)(Hb + base);
  *(float4*)&h[4] = *(const float4*)(Hb + base + 4);
  float4 i0 = *(const float4*)(Imv + base);
  float4 i1 = *(const float4*)(Imv + base + 4);
  f[0] = i0.x; f[1] = i0.y; f[2] = i0.z; f[3] = i0.w;
  f[4] = i1.x; f[5] = i1.y; f[6] = i1.z; f[7] = i1.w;
#pragma unroll
  for (int j = 0; j < 8; ++j) f[j] *= ((0xE8 >> j) & 1) ? -1.f : 1.f;
  if (m >= 1) {
    const float* rp0 = RF0 + (size_t)(r - 1) * NCOL + c;
    const float* rp1 = RF1 + (size_t)(r - 1) * NCOL + c;
#pragma unroll
    for (int j = 0; j < 8; ++j)
      f[j] += (rp0[j] + rp1[j]) * (((0xE8 >> j) & 1) ? -1.f : 1.f);
  }
  if (m < LLEN - 1) {
    const float* rn0 = RF0 + (size_t)(r + 1) * NCOL + KDIM + c;
    const float* rn1 = RF1 + (size_t)(r + 1) * NCOL + KDIM + c;
#pragma unroll
    for (int j = 0; j < 8; ++j) f[j] += rn0[j] + rn1[j];
  }
  float hn[8], av[8];
#pragma unroll
  for (int j = 0; j < 8; ++j) {
    float hv = h[j];
    float dr = (hv > 0.f && hv < 1.f) ? 1.f : ((hv == 0.f || hv == 1.f) ? 0.5f : 0.f);
    hn[j] = hv - 0.1f * (hv - dr * f[j]);
  }
  *(float4*)(Hb + base) = make_float4(hn[0], hn[1], hn[2], hn[3]);
  *(float4*)(Hb + base + 4) = make_float4(hn[4], hn[5], hn[6], hn[7]);
  if (!LAST) {
    short8 h8, l8;
#pragma unroll
    for (int j = 0; j < 8; ++j) {
      float a = clipf(hn[j]);
      unsigned short hi = f2bf(a);
      h8[j] = (short)hi;
      l8[j] = (short)f2bf(a - bf2f(hi));
    }
    size_t off = tso128(r >> 7, c >> 5, r & 127, c & 31);
    *(short8*)&Hhi[off] = h8;
    *(short8*)&Hlo[off] = l8;
  } else {
    if (!big) return;
#pragma unroll
    for (int j = 0; j < 8; ++j) av[j] = hn[j] * (((0xE8 >> j) & 1) ? -1.f : 1.f);
    float lm = 0.f;
#pragma unroll
    for (int j = 0; j < 8; ++j) lm = fmaxf(lm, fabsf(av[j]));
    red[tix] = lm; __syncthreads();
    for (int s = 128; s; s >>= 1) { if (tix < s) red[tix] = fmaxf(red[tix], red[tix + s]); __syncthreads(); }
    float mx = fmaxf(red[0], 1e-20f);
    float inv = dig_inv(mx);
    if (tix == 0) sA[r] = exp2f((float)(ilogbf(mx) + 2));
    char d1[8], d2[8];
#pragma unroll
    for (int j = 0; j < 8; ++j) {
      float tv = av[j] * inv;
      float f1 = rintf(tv);
      d1[j] = (char)(int)f1;
      d2[j] = (char)(int)rintf((tv - f1) * 128.f);
    }
    // A digit layout: [mtile][kt][4 kq][128 row][16]; thread t -> kt=t>>3, kq=(t>>1)&3, off=(t&1)*8
    size_t addr = (((size_t)(r >> 7) * 32 + (tix >> 3)) << 13) + ((size_t)((tix >> 1) & 3) << 11)
                + ((r & 127) << 4) + ((tix & 1) << 3);
    *(uint64_t*)&Ad1[addr] = *(uint64_t*)d1;
    *(uint64_t*)&Ad2[addr] = *(uint64_t*)d2;
  }
}

// ---- fallback logits GEMM (in-kernel bf16 conversion), used if ws too small ----
template <int AMODE>
__global__ __launch_bounds__(256) void k_gemm_split(const float* __restrict__ A,
                                                    const float* __restrict__ B,
                                                    float* __restrict__ C, int ldc) {
  __shared__ unsigned short Ah[128 * 32], Al[128 * 32];
  __shared__ unsigned short Bh[128 * 32], Bl[128 * 32];
  const int t = threadIdx.x;
  const int row0 = blockIdx.y * 128, col0 = blockIdx.x * 128;
  const int l = t & 63, w = t >> 6;
  const int wr = w >> 1, wc = w & 1;
  const int sr = t >> 3;
  const int cc = (t & 7) << 2;
  const int chunkb = cc >> 3;
  const int halfo = (cc >> 2) & 1;
  f32x4 acc[4][4];
#pragma unroll
  for (int i = 0; i < 4; ++i)
#pragma unroll
    for (int j = 0; j < 4; ++j) acc[i][j] = (f32x4)0.f;
  const float sA0 = 1.f;
  const float sA1 = (cc & 4) ? -1.f : 1.f;
  const float sA2 = sA1;
  const float sA3 = -1.f;
  for (int k0 = 0; k0 < KDIM; k0 += 32) {
    float4 va[4], vb[4];
#pragma unroll
    for (int i = 0; i < 4; ++i) {
      va[i] = *(const float4*)(A + (size_t)(row0 + sr + i * 32) * KDIM + k0 + cc);
      vb[i] = *(const float4*)(B + (size_t)(col0 + sr + i * 32) * KDIM + k0 + cc);
    }
    __syncthreads();
#pragma unroll
    for (int i = 0; i < 4; ++i) {
      int row = sr + i * 32;
      int idx = row * 32 + ((chunkb ^ (row & 3)) << 3) + (halfo << 2);
      float4 a = va[i];
      if (AMODE == 0) {
        a.x = clipf(a.x); a.y = clipf(a.y); a.z = clipf(a.z); a.w = clipf(a.w);
      } else {
        a.x *= sA0; a.y *= sA1; a.z *= sA2; a.w *= sA3;
      }
      ushort4 h4, l4;
      h4.x = f2bf(a.x); l4.x = f2bf(a.x - bf2f(h4.x));
      h4.y = f2bf(a.y); l4.y = f2bf(a.y - bf2f(h4.y));
      h4.z = f2bf(a.z); l4.z = f2bf(a.z - bf2f(h4.z));
      h4.w = f2bf(a.w); l4.w = f2bf(a.w - bf2f(h4.w));
      *(ushort4*)&Ah[idx] = h4;
      *(ushort4*)&Al[idx] = l4;
      float4 bb = vb[i];
      h4.x = f2bf(bb.x); l4.x = f2bf(bb.x - bf2f(h4.x));
      h4.y = f2bf(bb.y); l4.y = f2bf(bb.y - bf2f(h4.y));
      h4.z = f2bf(bb.z); l4.z = f2bf(bb.z - bf2f(h4.z));
      h4.w = f2bf(bb.w); l4.w = f2bf(bb.w - bf2f(h4.w));
      *(ushort4*)&Bh[idx] = h4;
      *(ushort4*)&Bl[idx] = l4;
    }
    __syncthreads();
    short8 ah[4], al[4], bh[4], bl[4];
#pragma unroll
    for (int mi = 0; mi < 4; ++mi) {
      int ar = wr * 64 + mi * 16 + (l & 15);
      int kc = (l >> 4) ^ (ar & 3);
      ah[mi] = *(short8*)&Ah[ar * 32 + kc * 8];
      al[mi] = *(short8*)&Al[ar * 32 + kc * 8];
      int br = wc * 64 + mi * 16 + (l & 15);
      int kb = (l >> 4) ^ (br & 3);
      bh[mi] = *(short8*)&Bh[br * 32 + kb * 8];
      bl[mi] = *(short8*)&Bl[br * 32 + kb * 8];
    }
#pragma unroll
    for (int mi = 0; mi < 4; ++mi)
#pragma unroll
      for (int ni = 0; ni < 4; ++ni) {
        acc[mi][ni] = __builtin_amdgcn_mfma_f32_16x16x32_bf16(ah[mi], bh[ni], acc[mi][ni], 0, 0, 0);
        acc[mi][ni] = __builtin_amdgcn_mfma_f32_16x16x32_bf16(ah[mi], bl[ni], acc[mi][ni], 0, 0, 0);
        acc[mi][ni] = __builtin_amdgcn_mfma_f32_16x16x32_bf16(al[mi], bh[ni], acc[mi][ni], 0, 0, 0);
      }
  }
#pragma unroll
  for (int mi = 0; mi < 4; ++mi)
#pragma unroll
    for (int ni = 0; ni < 4; ++ni) {
      int rg = row0 + wr * 64 + mi * 16 + (l >> 4) * 4;
      int cg = col0 + wc * 64 + ni * 16 + (l & 15);
#pragma unroll
      for (int j = 0; j < 4; ++j)
        C[(size_t)(rg + j) * ldc + cg] = acc[mi][ni][j];
    }
}

extern "C" void kernel_launch(void* const* d_in, const int* in_sizes, int n_in,
                              void* d_out, int out_size, void* d_ws, size_t ws_size,
                              hipStream_t stream) {
  const int*   x    = (const int*)d_in[0];
  const float* emb  = (const float*)d_in[1];
  const float* Win  = (const float*)d_in[2];
  const float* Wrec = (const float*)d_in[3];
  const float* Wout = (const float*)d_in[4];
  float* logits = (float*)d_out;

  char* base = (char*)d_ws;
  const size_t MB = 1ull << 20;
  float* Hbuf = (float*)(base + 0);
  float* Imv  = (float*)(base + 8 * MB);
  float* RF0  = (float*)(base + 16 * MB);
  float* RF1  = (float*)(base + 32 * MB);
  unsigned short* Hhi = (unsigned short*)(base + 48 * MB);
  unsigned short* Hlo = (unsigned short*)(base + 52 * MB);
  unsigned short* Mhi = (unsigned short*)(base + 56 * MB);
  unsigned short* Mlo = (unsigned short*)(base + 72 * MB);
  float* scl = (float*)(base + 88 * MB);
  float* sA  = (float*)(base + 88 * MB + 4096);
  char* Wd1  = base + 88 * MB + 8192;
  char* Wd2  = Wd1 + (size_t)VOCAB * KDIM;
  // A digits reuse the MRT space (MRT last read by final k_gemm_pre, before k_update<1>)
  char* Ad1  = (char*)Mhi;
  char* Ad2  = (char*)Mlo;

  const size_t need = (size_t)(Wd2 - base) + (size_t)VOCAB * KDIM;
  const bool big = ws_size >= need;

  hipMemsetAsync(Hbuf, 0, 8 * MB, stream);
  hipMemsetAsync(Hhi, 0, 8 * MB, stream);          // Hhi+Hlo contiguous
  if (big) hipMemsetAsync(scl, 0, 16, stream);
  k_build_mrt_split<<<32768, 256, 0, stream>>>(Wrec, Mhi, Mlo);
  k_input_mv<<<256, 256, 0, stream>>>(x, emb, Win, Imv);
  if (big) {
    k_wout_max<<<2048, 256, 0, stream>>>(Wout, scl);
    k_dig_wout<<<4000, 256, 0, stream>>>(Wout, scl, Wd1, Wd2);
  }

  for (int it = 0; it < 5; ++it) {
    k_gemm_pre<<<512, 256, 0, stream>>>(Hhi, Hlo, Mhi, Mlo, RF0, RF1);
    if (it < 4) k_update<0><<<1024, 256, 0, stream>>>(Hbuf, Imv, RF0, RF1, Hhi, Hlo, sA, Ad1, Ad2, big);
    else        k_update<1><<<1024, 256, 0, stream>>>(Hbuf, Imv, RF0, RF1, Hhi, Hlo, sA, Ad1, Ad2, big);
  }

  if (big) {
    k_gemm_i8<<<1000, 512, 0, stream>>>(Ad1, Ad2, Wd1, Wd2, scl, sA, logits);
  } else {
    k_gemm_split<1><<<dim3(VOCAB / 128, NROWS / 128), 256, 0, stream>>>(Hbuf, Wout, logits, VOCAB);
  }
}

// Round 7
// 743.611 us; speedup vs baseline: 1.2243x; 1.0093x over previous
//
#include <hip/hip_runtime.h>
#include <cstddef>
#include <cstdint>

#define VOCAB  32000
#define EMB    256
#define NB     8
#define KDIM   2048        /* H*NB */
#define NROWS  1024        /* B*L  */
#define NCOL   4096        /* 2*KDIM */
#define LLEN   256

typedef __attribute__((ext_vector_type(8))) short short8;
typedef __attribute__((ext_vector_type(4))) float f32x4;
typedef __attribute__((ext_vector_type(16))) float f32x16;
typedef __attribute__((ext_vector_type(4))) int i32x4;
typedef __attribute__((ext_vector_type(16))) int i32x16;

__device__ __forceinline__ float cl3_sign(int a, int b) {
  int x = a >> 1, p = 0;
  while (x) { p ^= __popc(x & b) & 1; x >>= 1; }
  return p ? -1.f : 1.f;   // metric all +1 for Cl(3,0)
}

__device__ __forceinline__ float clipf(float v) { return fminf(fmaxf(v, 0.f), 1.f); }

__device__ __forceinline__ unsigned short f2bf(float f) {
  unsigned u = __float_as_uint(f);
  u += 0x7FFF + ((u >> 16) & 1);           // round-to-nearest-even
  return (unsigned short)(u >> 16);
}
__device__ __forceinline__ float bf2f(unsigned short h) {
  return __uint_as_float(((unsigned)h) << 16);
}

// chunk-major tiled offset (bf16 planes, free phase): tile = 128 rows x 32 k as [4 kchunk][128 row][8 k]
__device__ __forceinline__ size_t tso128(int tr, int tk, int r, int kk) {
  return ((size_t)(tr * 64 + tk) << 12) + ((size_t)((kk >> 3) & 3) << 10) + (r << 3) + (kk & 7);
}

__device__ __forceinline__ void gload16(const void* g, void* l) {
  __builtin_amdgcn_global_load_lds((const __attribute__((address_space(1))) uint32_t*)g,
                                   (__attribute__((address_space(3))) uint32_t*)l, 16, 0, 0);
}

// scale: s = 2^(ilogb(max)+2); inv = 128/s; digits in [-64,64]
__device__ __forceinline__ float dig_inv(float mx) {
  return exp2f((float)(5 - ilogbf(fmaxf(mx, 1e-20f))));
}

// ---- MRT split build: B^T [4096][2048] -> chunk-major tiled hi/lo bf16 ----
__global__ void k_build_mrt_split(const float* __restrict__ Wrec,
                                  unsigned short* __restrict__ Mhi,
                                  unsigned short* __restrict__ Mlo) {
  int idx = blockIdx.x * blockDim.x + threadIdx.x;
  int k = idx & (KDIM - 1);
  int n = idx >> 11;
  int h = k >> 3, i = k & 7;
  float v;
  if (n < KDIM) {
    int g = n >> 3, kb = n & 7;
    int j = i ^ kb;
    v = Wrec[(size_t)g * KDIM + h * NB + j] * cl3_sign(i, j);
  } else {
    int c = n - KDIM;
    int p = c >> 3, q = c & 7;
    int j = q ^ i;
    v = cl3_sign(i, i) * cl3_sign(q, j) * Wrec[(size_t)h * KDIM + p * NB + j];
  }
  unsigned short hi = f2bf(v);
  unsigned short lo = f2bf(v - bf2f(hi));
  size_t off = tso128(n >> 7, k >> 5, n & 127, k & 31);
  Mhi[off] = hi; Mlo[off] = lo;
}

// ---- global absmax of Wout -> scl[1] ----
__global__ __launch_bounds__(256) void k_wout_max(const float* __restrict__ W, float* __restrict__ scl) {
  __shared__ float red[256];
  const int t = threadIdx.x;
  size_t stride = (size_t)gridDim.x * 256;
  float m = 0.f;
  for (size_t i = (size_t)blockIdx.x * 256 + t; i < (size_t)VOCAB * KDIM / 4; i += stride) {
    float4 v = ((const float4*)W)[i];
    m = fmaxf(m, fmaxf(fmaxf(fabsf(v.x), fabsf(v.y)), fmaxf(fabsf(v.z), fabsf(v.w))));
  }
  red[t] = m; __syncthreads();
  for (int s = 128; s; s >>= 1) { if (t < s) red[t] = fmaxf(red[t], red[t + s]); __syncthreads(); }
  if (t == 0) atomicMax((unsigned*)(scl + 1), __float_as_uint(red[0]));
}

// ---- Wout digitizer: one block = one [256 v-rows x 64 k] slab -> i8 planes [4 kq][256 row][16] ----
__global__ __launch_bounds__(256) void k_dig_wout(const float* __restrict__ W,
                                                  const float* __restrict__ scl,
                                                  char* __restrict__ Wd1,
                                                  char* __restrict__ Wd2) {
  __shared__ char l1[16384], l2[16384];
  const int tn = blockIdx.x >> 5;          // 125 n-tiles
  const int kt = blockIdx.x & 31;          // 32 k-tiles
  const int t = threadIdx.x;
  const float inv = dig_inv(scl[1]);
#pragma unroll
  for (int p = 0; p < 8; ++p) {
    int ci = p * 256 + t;                  // 0..2047 chunk of 8 floats
    int row = ci >> 3, koff = (ci & 7) * 8;
    const float* src = W + (size_t)(tn * 256 + row) * KDIM + kt * 64 + koff;
    float e[8];
    *(float4*)&e[0] = *(const float4*)src;
    *(float4*)&e[4] = *(const float4*)(src + 4);
    char d1[8], d2[8];
#pragma unroll
    for (int j = 0; j < 8; ++j) {
      float tv = e[j] * inv;
      float f1 = rintf(tv);
      d1[j] = (char)(int)f1;
      d2[j] = (char)(int)rintf((tv - f1) * 128.f);
    }
    int lo = ((koff >> 4) << 12) + (row << 4) + (koff & 8);
    *(uint64_t*)&l1[lo] = *(uint64_t*)d1;
    *(uint64_t*)&l2[lo] = *(uint64_t*)d2;
  }
  __syncthreads();
  size_t ob = ((size_t)blockIdx.x << 14) + t * 64;
#pragma unroll
  for (int q = 0; q < 4; ++q) {
    *(i32x4*)&Wd1[ob + q * 16] = *(const i32x4*)&l1[t * 64 + q * 16];
    *(i32x4*)&Wd2[ob + q * 16] = *(const i32x4*)&l2[t * 64 + q * 16];
  }
}

// input_mv[r][h*8+i] = sum_d emb[x[r]][d] * Win[h][d][i]; one block = 4 rows
__global__ __launch_bounds__(256) void k_input_mv(const int* __restrict__ x,
                                                  const float* __restrict__ emb,
                                                  const float* __restrict__ Win,
                                                  float* __restrict__ out) {
  __shared__ float se[4][EMB];
  int r0 = blockIdx.x * 4;
  int t = threadIdx.x;
  for (int rr = 0; rr < 4; ++rr) {
    int tok = x[r0 + rr];
    se[rr][t] = emb[(size_t)tok * EMB + t];
  }
  __syncthreads();
  float acc[4][8];
#pragma unroll
  for (int rr = 0; rr < 4; ++rr)
#pragma unroll
    for (int i = 0; i < 8; ++i) acc[rr][i] = 0.f;
  const float* wrow = Win + (size_t)t * KDIM;
  for (int d = 0; d < EMB; ++d) {
    float4 w0 = *(const float4*)(wrow + d * 8);
    float4 w1 = *(const float4*)(wrow + d * 8 + 4);
#pragma unroll
    for (int rr = 0; rr < 4; ++rr) {
      float e = se[rr][d];
      acc[rr][0] += e * w0.x; acc[rr][1] += e * w0.y;
      acc[rr][2] += e * w0.z; acc[rr][3] += e * w0.w;
      acc[rr][4] += e * w1.x; acc[rr][5] += e * w1.y;
      acc[rr][6] += e * w1.z; acc[rr][7] += e * w1.w;
    }
  }
  for (int rr = 0; rr < 4; ++rr) {
    float4* o = (float4*)(out + (size_t)(r0 + rr) * KDIM + t * 8);
    o[0] = make_float4(acc[rr][0], acc[rr][1], acc[rr][2], acc[rr][3]);
    o[1] = make_float4(acc[rr][4], acc[rr][5], acc[rr][6], acc[rr][7]);
  }
}

// ---- free-phase bf16 split GEMM, 3-buffer counted-vmcnt pipeline ----
// tile 128x256, 8 waves (2M x 4N, 64x64 each), BK=32, split-K x2 (halves -> RF0/RF1).
// Per-output accumulation order (kt asc, s asc, hh->hl->lh) is IDENTICAL to the
// previous structure => bit-identical free-phase trajectory.
__global__ __launch_bounds__(512, 1) void k_gemm_pre(const unsigned short* __restrict__ Ahi,
                                                     const unsigned short* __restrict__ Alo,
                                                     const unsigned short* __restrict__ Bhi,
                                                     const unsigned short* __restrict__ Blo,
                                                     float* __restrict__ RF0,
                                                     float* __restrict__ RF1) {
  __shared__ __align__(16) char lds[3 * 49152];   // 3 x {Ahi 8K | Alo 8K | Bhi 16K | Blo 16K}
  const int b = blockIdx.x;                        // 256 blocks
  const int lin = (b & 7) * 32 + (b >> 3);         // XCD-chunked (256 % 8 == 0)
  const int half = lin >> 7;
  const int inner = lin & 127;
  const int tm = inner & 7, tn = inner >> 3;       // 8 consecutive lin share B panel
  const int ktbase = half << 5;
  float* __restrict__ C = half ? RF1 : RF0;
  const int t = threadIdx.x;
  const int l = t & 63, w = t >> 6;
  const int wr = w >> 2, wc = w & 3;

  const char* aHg  = (const char*)Ahi + (((size_t)tm * 64) << 13) + (t << 4);
  const char* aLg  = (const char*)Alo + (((size_t)tm * 64) << 13) + (t << 4);
  const char* bHg0 = (const char*)Bhi + (((size_t)(tn * 2) * 64) << 13) + (t << 4);
  const char* bHg1 = (const char*)Bhi + (((size_t)(tn * 2 + 1) * 64) << 13) + (t << 4);
  const char* bLg0 = (const char*)Blo + (((size_t)(tn * 2) * 64) << 13) + (t << 4);
  const char* bLg1 = (const char*)Blo + (((size_t)(tn * 2 + 1) * 64) << 13) + (t << 4);
  const int wub = w << 10;                         // wave-uniform LDS dest

  f32x16 acc[2][2];
#pragma unroll
  for (int i = 0; i < 2; ++i)
#pragma unroll
    for (int j = 0; j < 2; ++j) acc[i][j] = (f32x16)0.f;

  auto STAGE_H = [&](int bf, int kt, int hh) {
    char* lb = &lds[bf * 49152];
    size_t kb = (size_t)kt << 13;
    if (hh == 0) {
      gload16(aHg + kb, lb + wub);
      gload16(aLg + kb, lb + 8192 + wub);
      gload16(bHg0 + kb, lb + 16384 + wub);
    } else {
      gload16(bHg1 + kb, lb + 24576 + wub);
      gload16(bLg0 + kb, lb + 32768 + wub);
      gload16(bLg1 + kb, lb + 40960 + wub);
    }
  };

  STAGE_H(0, ktbase, 0); STAGE_H(0, ktbase, 1);
  STAGE_H(1, ktbase + 1, 0); STAGE_H(1, ktbase + 1, 1);

  const int ra  = wr * 64 + (l & 31);              // A row base (+mi*32)
  const int rbb = wc * 64 + (l & 31);              // B row base (+nj*32), 0..255
  int cur = 0;
  for (int kt = 0; kt < 32; ++kt) {
    int pf = cur + 2; if (pf >= 3) pf -= 3;
    if (kt < 31) { asm volatile("s_waitcnt vmcnt(6)" ::: "memory"); }
    else         { asm volatile("s_waitcnt vmcnt(0)" ::: "memory"); }
    __builtin_amdgcn_s_barrier();
    const char* lb = &lds[cur * 49152];
#pragma unroll
    for (int s = 0; s < 2; ++s) {
      const int kc = ((s << 1) + (l >> 5)) << 11;  // kchunk byte offset
      short8 ah[2], al[2], bh[2], bl[2];
#pragma unroll
      for (int mi = 0; mi < 2; ++mi) {
        int off = kc + ((ra + mi * 32) << 4);
        ah[mi] = *(const short8*)(lb + off);
        al[mi] = *(const short8*)(lb + 8192 + off);
      }
#pragma unroll
      for (int nj = 0; nj < 2; ++nj) {
        int rb = rbb + nj * 32;
        int off = ((rb >> 7) << 13) + kc + ((rb & 127) << 4);
        bh[nj] = *(const short8*)(lb + 16384 + off);
        bl[nj] = *(const short8*)(lb + 32768 + off);
      }
      if (kt + 2 < 32) STAGE_H(pf, ktbase + kt + 2, s);
      __builtin_amdgcn_s_setprio(1);
#pragma unroll
      for (int mi = 0; mi < 2; ++mi)
#pragma unroll
        for (int nj = 0; nj < 2; ++nj) {
          acc[mi][nj] = __builtin_amdgcn_mfma_f32_32x32x16_bf16(ah[mi], bh[nj], acc[mi][nj], 0, 0, 0);
          acc[mi][nj] = __builtin_amdgcn_mfma_f32_32x32x16_bf16(ah[mi], bl[nj], acc[mi][nj], 0, 0, 0);
          acc[mi][nj] = __builtin_amdgcn_mfma_f32_32x32x16_bf16(al[mi], bh[nj], acc[mi][nj], 0, 0, 0);
        }
      __builtin_amdgcn_s_setprio(0);
    }
    cur = (cur == 2) ? 0 : cur + 1;
  }

  const int rg0 = tm * 128 + wr * 64 + ((l >> 5) << 2);
  const int cg0 = tn * 256 + wc * 64 + (l & 31);
#pragma unroll
  for (int mi = 0; mi < 2; ++mi)
#pragma unroll
    for (int nj = 0; nj < 2; ++nj) {
      f32x16 v = acc[mi][nj];
#pragma unroll
      for (int g = 0; g < 16; ++g) {
        int rr = (g & 3) + ((g >> 2) << 3);
        C[(size_t)(rg0 + mi * 32 + rr) * NCOL + cg0 + nj * 32] = v[g];
      }
    }
}

// ---- i8 digit GEMM (logits), counted-vmcnt 3-buffer pipeline ----
// tile 128x256, 8 waves (2M x 4N, 64x64 each), BK=64, 1 raw barrier per K-tile.
__global__ __launch_bounds__(512, 1) void k_gemm_i8(const char* __restrict__ Ad1,
                                                    const char* __restrict__ Ad2,
                                                    const char* __restrict__ Bd1,
                                                    const char* __restrict__ Bd2,
                                                    const float* __restrict__ scl,
                                                    const float* __restrict__ sA,
                                                    float* __restrict__ C) {
  __shared__ __align__(16) char lds[3 * 49152];   // 3 x {A1 8K | A2 8K | B1 16K | B2 16K}
  const int b = blockIdx.x;                       // 1000 blocks
  const int lin = (b & 7) * 125 + (b >> 3);       // XCD-chunked (1000 % 8 == 0)
  const int tm = lin & 7, tn = lin >> 3;          // 8 consecutive lin share B panel
  const int t = threadIdx.x;
  const int l = t & 63, w = t >> 6;
  const int wr = w >> 2, wc = w & 3;

  const char* a1g = Ad1 + ((size_t)tm * 32 << 13) + (t << 4);
  const char* a2g = Ad2 + ((size_t)tm * 32 << 13) + (t << 4);
  const char* b1g = Bd1 + ((size_t)tn * 32 << 14) + (t << 4);
  const char* b2g = Bd2 + ((size_t)tn * 32 << 14) + (t << 4);
  const int wub = w << 10;                        // wave-uniform LDS dest

  const int la = (l & 31) << 4;
  const int rowa0 = (wr * 64 + 0) << 4, rowa1 = (wr * 64 + 32) << 4;
  const int rowb0 = (wc * 64 + 0) << 4, rowb1 = (wc * 64 + 32) << 4;

  i32x16 acc1[2][2], acc2[2][2];
#pragma unroll
  for (int i = 0; i < 2; ++i)
#pragma unroll
    for (int j = 0; j < 2; ++j) { acc1[i][j] = (i32x16)0; acc2[i][j] = (i32x16)0; }

  auto STAGE_H = [&](int bf, int kt, int h) {
    char* lb = &lds[bf * 49152];
    size_t ka = (size_t)kt << 13, kb = (size_t)kt << 14;
    if (h == 0) {
      gload16(a1g + ka, lb + wub);
      gload16(a2g + ka, lb + 8192 + wub);
      gload16(b1g + kb, lb + 16384 + wub);
    } else {
      gload16(b1g + kb + 8192, lb + 24576 + wub);
      gload16(b2g + kb, lb + 32768 + wub);
      gload16(b2g + kb + 8192, lb + 40960 + wub);
    }
  };

  STAGE_H(0, 0, 0); STAGE_H(0, 0, 1);
  STAGE_H(1, 1, 0); STAGE_H(1, 1, 1);

  int cur = 0;
  for (int kt = 0; kt < 32; ++kt) {
    int pf = cur + 2; if (pf >= 3) pf -= 3;
    if (kt < 31) { asm volatile("s_waitcnt vmcnt(6)" ::: "memory"); }
    else         { asm volatile("s_waitcnt vmcnt(0)" ::: "memory"); }
    __builtin_amdgcn_s_barrier();
    const char* lb = &lds[cur * 49152];
#pragma unroll
    for (int s = 0; s < 2; ++s) {
      const int kqa = ((s << 1) + (l >> 5)) << 11;   // A plane kq offset (x2048)
      const int kqb = ((s << 1) + (l >> 5)) << 12;   // B plane kq offset (x4096)
      i32x4 a1[2], a2[2], b1[2], b2[2];
      a1[0] = *(const i32x4*)(lb + kqa + rowa0 + la);
      a1[1] = *(const i32x4*)(lb + kqa + rowa1 + la);
      a2[0] = *(const i32x4*)(lb + 8192 + kqa + rowa0 + la);
      a2[1] = *(const i32x4*)(lb + 8192 + kqa + rowa1 + la);
      b1[0] = *(const i32x4*)(lb + 16384 + kqb + rowb0 + la);
      b1[1] = *(const i32x4*)(lb + 16384 + kqb + rowb1 + la);
      b2[0] = *(const i32x4*)(lb + 32768 + kqb + rowb0 + la);
      b2[1] = *(const i32x4*)(lb + 32768 + kqb + rowb1 + la);
      if (kt + 2 < 32) STAGE_H(pf, kt + 2, s);
      __builtin_amdgcn_s_setprio(1);
#pragma unroll
      for (int mi = 0; mi < 2; ++mi)
#pragma unroll
        for (int nj = 0; nj < 2; ++nj) {
          acc1[mi][nj] = __builtin_amdgcn_mfma_i32_32x32x32_i8(a1[mi], b1[nj], acc1[mi][nj], 0, 0, 0);
          acc2[mi][nj] = __builtin_amdgcn_mfma_i32_32x32x32_i8(a1[mi], b2[nj], acc2[mi][nj], 0, 0, 0);
          acc2[mi][nj] = __builtin_amdgcn_mfma_i32_32x32x32_i8(a2[mi], b1[nj], acc2[mi][nj], 0, 0, 0);
        }
      __builtin_amdgcn_s_setprio(0);
    }
    cur = (cur == 2) ? 0 : cur + 1;
  }

  const float sB = exp2f((float)(ilogbf(scl[1]) + 2));
  const int rbase = tm * 128 + wr * 64 + ((l >> 5) << 2);
  const int cbase = tn * 256 + wc * 64 + (l & 31);
#pragma unroll
  for (int mi = 0; mi < 2; ++mi)
#pragma unroll
    for (int nj = 0; nj < 2; ++nj) {
#pragma unroll
      for (int g = 0; g < 16; ++g) {
        int rr = (g & 3) + ((g >> 2) << 3);
        int row = rbase + mi * 32 + rr;
        float c1 = sA[row] * sB * (1.f / 16384.f);
        C[(size_t)row * VOCAB + cbase + nj * 32] =
            fmaf((float)acc2[mi][nj][g], c1 * (1.f / 128.f), (float)acc1[mi][nj][g] * c1);
      }
    }
}

// h <- h - 0.1*(h - drho(h)*(inmv*sq + rec_prev*sq + fwd_next))
// LAST=0: emit bf16 hi/lo planes for next free-phase GEMM
// LAST=1: per-row scale + i8 digitization of h*bladeSign (block = one row)
template <int LAST>
__global__ __launch_bounds__(256) void k_update(float* __restrict__ Hb, const float* __restrict__ Imv,
                                                const float* __restrict__ RF0, const float* __restrict__ RF1,
                                                unsigned short* __restrict__ Hhi,
                                                unsigned short* __restrict__ Hlo,
                                                float* __restrict__ sA,
                                                char* __restrict__ Ad1,
                                                char* __restrict__ Ad2,
                                                int big) {
  __shared__ float red[256];
  int tix = threadIdx.x;
  int idx = blockIdx.x * 256 + tix;
  int r = idx >> 8;
  int c = (idx & 255) << 3;
  int m = r & (LLEN - 1);
  const size_t base = (size_t)r * KDIM + c;
  float h[8], f[8];
  *(float4*)&h[0] = *(const float4*)(Hb + base);
  *(float4*)&h[4] = *(const float4*)(Hb + base + 4);
  float4 i0 = *(const float4*)(Imv + base);
  float4 i1 = *(const float4*)(Imv + base + 4);
  f[0] = i0.x; f[1] = i0.y; f[2] = i0.z; f[3] = i0.w;
  f[4] = i1.x; f[5] = i1.y; f[6] = i1.z; f[7] = i1.w;
#pragma unroll
  for (int j = 0; j < 8; ++j) f[j] *= ((0xE8 >> j) & 1) ? -1.f : 1.f;
  if (m >= 1) {
    const float* rp0 = RF0 + (size_t)(r - 1) * NCOL + c;
    const float* rp1 = RF1 + (size_t)(r - 1) * NCOL + c;
#pragma unroll
    for (int j = 0; j < 8; ++j)
      f[j] += (rp0[j] + rp1[j]) * (((0xE8 >> j) & 1) ? -1.f : 1.f);
  }
  if (m < LLEN - 1) {
    const float* rn0 = RF0 + (size_t)(r + 1) * NCOL + KDIM + c;
    const float* rn1 = RF1 + (size_t)(r + 1) * NCOL + KDIM + c;
#pragma unroll
    for (int j = 0; j < 8; ++j) f[j] += rn0[j] + rn1[j];
  }
  float hn[8], av[8];
#pragma unroll
  for (int j = 0; j < 8; ++j) {
    float hv = h[j];
    float dr = (hv > 0.f && hv < 1.f) ? 1.f : ((hv == 0.f || hv == 1.f) ? 0.5f : 0.f);
    hn[j] = hv - 0.1f * (hv - dr * f[j]);
  }
  *(float4*)(Hb + base) = make_float4(hn[0], hn[1], hn[2], hn[3]);
  *(float4*)(Hb + base + 4) = make_float4(hn[4], hn[5], hn[6], hn[7]);
  if (!LAST) {
    short8 h8, l8;
#pragma unroll
    for (int j = 0; j < 8; ++j) {
      float a = clipf(hn[j]);
      unsigned short hi = f2bf(a);
      h8[j] = (short)hi;
      l8[j] = (short)f2bf(a - bf2f(hi));
    }
    size_t off = tso128(r >> 7, c >> 5, r & 127, c & 31);
    *(short8*)&Hhi[off] = h8;
    *(short8*)&Hlo[off] = l8;
  } else {
    if (!big) return;
#pragma unroll
    for (int j = 0; j < 8; ++j) av[j] = hn[j] * (((0xE8 >> j) & 1) ? -1.f : 1.f);
    float lm = 0.f;
#pragma unroll
    for (int j = 0; j < 8; ++j) lm = fmaxf(lm, fabsf(av[j]));
    red[tix] = lm; __syncthreads();
    for (int s = 128; s; s >>= 1) { if (tix < s) red[tix] = fmaxf(red[tix], red[tix + s]); __syncthreads(); }
    float mx = fmaxf(red[0], 1e-20f);
    float inv = dig_inv(mx);
    if (tix == 0) sA[r] = exp2f((float)(ilogbf(mx) + 2));
    char d1[8], d2[8];
#pragma unroll
    for (int j = 0; j < 8; ++j) {
      float tv = av[j] * inv;
      float f1 = rintf(tv);
      d1[j] = (char)(int)f1;
      d2[j] = (char)(int)rintf((tv - f1) * 128.f);
    }
    // A digit layout: [mtile][kt][4 kq][128 row][16]; thread t -> kt=t>>3, kq=(t>>1)&3, off=(t&1)*8
    size_t addr = (((size_t)(r >> 7) * 32 + (tix >> 3)) << 13) + ((size_t)((tix >> 1) & 3) << 11)
                + ((r & 127) << 4) + ((tix & 1) << 3);
    *(uint64_t*)&Ad1[addr] = *(uint64_t*)d1;
    *(uint64_t*)&Ad2[addr] = *(uint64_t*)d2;
  }
}

// ---- fallback logits GEMM (in-kernel bf16 conversion), used if ws too small ----
template <int AMODE>
__global__ __launch_bounds__(256) void k_gemm_split(const float* __restrict__ A,
                                                    const float* __restrict__ B,
                                                    float* __restrict__ C, int ldc) {
  __shared__ unsigned short Ah[128 * 32], Al[128 * 32];
  __shared__ unsigned short Bh[128 * 32], Bl[128 * 32];
  const int t = threadIdx.x;
  const int row0 = blockIdx.y * 128, col0 = blockIdx.x * 128;
  const int l = t & 63, w = t >> 6;
  const int wr = w >> 1, wc = w & 1;
  const int sr = t >> 3;
  const int cc = (t & 7) << 2;
  const int chunkb = cc >> 3;
  const int halfo = (cc >> 2) & 1;
  f32x4 acc[4][4];
#pragma unroll
  for (int i = 0; i < 4; ++i)
#pragma unroll
    for (int j = 0; j < 4; ++j) acc[i][j] = (f32x4)0.f;
  const float sA0 = 1.f;
  const float sA1 = (cc & 4) ? -1.f : 1.f;
  const float sA2 = sA1;
  const float sA3 = -1.f;
  for (int k0 = 0; k0 < KDIM; k0 += 32) {
    float4 va[4], vb[4];
#pragma unroll
    for (int i = 0; i < 4; ++i) {
      va[i] = *(const float4*)(A + (size_t)(row0 + sr + i * 32) * KDIM + k0 + cc);
      vb[i] = *(const float4*)(B + (size_t)(col0 + sr + i * 32) * KDIM + k0 + cc);
    }
    __syncthreads();
#pragma unroll
    for (int i = 0; i < 4; ++i) {
      int row = sr + i * 32;
      int idx = row * 32 + ((chunkb ^ (row & 3)) << 3) + (halfo << 2);
      float4 a = va[i];
      if (AMODE == 0) {
        a.x = clipf(a.x); a.y = clipf(a.y); a.z = clipf(a.z); a.w = clipf(a.w);
      } else {
        a.x *= sA0; a.y *= sA1; a.z *= sA2; a.w *= sA3;
      }
      ushort4 h4, l4;
      h4.x = f2bf(a.x); l4.x = f2bf(a.x - bf2f(h4.x));
      h4.y = f2bf(a.y); l4.y = f2bf(a.y - bf2f(h4.y));
      h4.z = f2bf(a.z); l4.z = f2bf(a.z - bf2f(h4.z));
      h4.w = f2bf(a.w); l4.w = f2bf(a.w - bf2f(h4.w));
      *(ushort4*)&Ah[idx] = h4;
      *(ushort4*)&Al[idx] = l4;
      float4 bb = vb[i];
      h4.x = f2bf(bb.x); l4.x = f2bf(bb.x - bf2f(h4.x));
      h4.y = f2bf(bb.y); l4.y = f2bf(bb.y - bf2f(h4.y));
      h4.z = f2bf(bb.z); l4.z = f2bf(bb.z - bf2f(h4.z));
      h4.w = f2bf(bb.w); l4.w = f2bf(bb.w - bf2f(h4.w));
      *(ushort4*)&Bh[idx] = h4;
      *(ushort4*)&Bl[idx] = l4;
    }
    __syncthreads();
    short8 ah[4], al[4], bh[4], bl[4];
#pragma unroll
    for (int mi = 0; mi < 4; ++mi) {
      int ar = wr * 64 + mi * 16 + (l & 15);
      int kc = (l >> 4) ^ (ar & 3);
      ah[mi] = *(short8*)&Ah[ar * 32 + kc * 8];
      al[mi] = *(short8*)&Al[ar * 32 + kc * 8];
      int br = wc * 64 + mi * 16 + (l & 15);
      int kb = (l >> 4) ^ (br & 3);
      bh[mi] = *(short8*)&Bh[br * 32 + kb * 8];
      bl[mi] = *(short8*)&Bl[br * 32 + kb * 8];
    }
#pragma unroll
    for (int mi = 0; mi < 4; ++mi)
#pragma unroll
      for (int ni = 0; ni < 4; ++ni) {
        acc[mi][ni] = __builtin_amdgcn_mfma_f32_16x16x32_bf16(ah[mi], bh[ni], acc[mi][ni], 0, 0, 0);
        acc[mi][ni] = __builtin_amdgcn_mfma_f32_16x16x32_bf16(ah[mi], bl[ni], acc[mi][ni], 0, 0, 0);
        acc[mi][ni] = __builtin_amdgcn_mfma_f32_16x16x32_bf16(al[mi], bh[ni], acc[mi][ni], 0, 0, 0);
      }
  }
#pragma unroll
  for (int mi = 0; mi < 4; ++mi)
#pragma unroll
    for (int ni = 0; ni < 4; ++ni) {
      int rg = row0 + wr * 64 + mi * 16 + (l >> 4) * 4;
      int cg = col0 + wc * 64 + ni * 16 + (l & 15);
#pragma unroll
      for (int j = 0; j < 4; ++j)
        C[(size_t)(rg + j) * ldc + cg] = acc[mi][ni][j];
    }
}

extern "C" void kernel_launch(void* const* d_in, const int* in_sizes, int n_in,
                              void* d_out, int out_size, void* d_ws, size_t ws_size,
                              hipStream_t stream) {
  const int*   x    = (const int*)d_in[0];
  const float* emb  = (const float*)d_in[1];
  const float* Win  = (const float*)d_in[2];
  const float* Wrec = (const float*)d_in[3];
  const float* Wout = (const float*)d_in[4];
  float* logits = (float*)d_out;

  char* base = (char*)d_ws;
  const size_t MB = 1ull << 20;
  float* Hbuf = (float*)(base + 0);
  float* Imv  = (float*)(base + 8 * MB);
  float* RF0  = (float*)(base + 16 * MB);
  float* RF1  = (float*)(base + 32 * MB);
  unsigned short* Hhi = (unsigned short*)(base + 48 * MB);
  unsigned short* Hlo = (unsigned short*)(base + 52 * MB);
  unsigned short* Mhi = (unsigned short*)(base + 56 * MB);
  unsigned short* Mlo = (unsigned short*)(base + 72 * MB);
  float* scl = (float*)(base + 88 * MB);
  float* sA  = (float*)(base + 88 * MB + 4096);
  char* Wd1  = base + 88 * MB + 8192;
  char* Wd2  = Wd1 + (size_t)VOCAB * KDIM;
  // A digits reuse the MRT space (MRT last read by final k_gemm_pre, before k_update<1>)
  char* Ad1  = (char*)Mhi;
  char* Ad2  = (char*)Mlo;

  const size_t need = (size_t)(Wd2 - base) + (size_t)VOCAB * KDIM;
  const bool big = ws_size >= need;

  hipMemsetAsync(Hbuf, 0, 8 * MB, stream);
  hipMemsetAsync(Hhi, 0, 8 * MB, stream);          // Hhi+Hlo contiguous
  if (big) hipMemsetAsync(scl, 0, 16, stream);
  k_build_mrt_split<<<32768, 256, 0, stream>>>(Wrec, Mhi, Mlo);
  k_input_mv<<<256, 256, 0, stream>>>(x, emb, Win, Imv);
  if (big) {
    k_wout_max<<<2048, 256, 0, stream>>>(Wout, scl);
    k_dig_wout<<<4000, 256, 0, stream>>>(Wout, scl, Wd1, Wd2);
  }

  for (int it = 0; it < 5; ++it) {
    k_gemm_pre<<<256, 512, 0, stream>>>(Hhi, Hlo, Mhi, Mlo, RF0, RF1);
    if (it < 4) k_update<0><<<1024, 256, 0, stream>>>(Hbuf, Imv, RF0, RF1, Hhi, Hlo, sA, Ad1, Ad2, big);
    else        k_update<1><<<1024, 256, 0, stream>>>(Hbuf, Imv, RF0, RF1, Hhi, Hlo, sA, Ad1, Ad2, big);
  }

  if (big) {
    k_gemm_i8<<<1000, 512, 0, stream>>>(Ad1, Ad2, Wd1, Wd2, scl, sA, logits);
  } else {
    k_gemm_split<1><<<dim3(VOCAB / 128, NROWS / 128), 256, 0, stream>>>(Hbuf, Wout, logits, VOCAB);
  }
}